// Round 2
// baseline (4831.679 us; speedup 1.0000x reference)
//
#include <hip/hip_runtime.h>
#include <stdint.h>

#define N_NODES 50000
#define N_EDGES 640000
#define DIM 128
#define IN_DIM 64
#define LAYERS 5
#define BN_EPS 1e-5f

typedef __attribute__((ext_vector_type(8))) short short8;
typedef __attribute__((ext_vector_type(4))) float f32x4;

__device__ __forceinline__ unsigned short f32_to_bf16(float f) {
    uint32_t u = __float_as_uint(f);
    u += 0x7fffu + ((u >> 16) & 1u);
    return (unsigned short)(u >> 16);
}
__device__ __forceinline__ float bf16_to_f32(unsigned short h) {
    return __uint_as_float(((uint32_t)h) << 16);
}

// ---- weights: W[L][K][NN] -> WT_hi/WT_lo[L][NN][K] (split bf16) ----
__global__ void wtrans(const float* __restrict__ W, unsigned short* __restrict__ WH,
                       unsigned short* __restrict__ WL, int K, int NN, int total) {
    int idx = blockIdx.x * 256 + threadIdx.x;
    if (idx >= total) return;
    int per = K * NN;
    int l = idx / per;
    int r = idx - l * per;
    int k = r / NN;
    int n = r - k * NN;
    float v = W[idx];
    unsigned short hi = f32_to_bf16(v);
    unsigned short lo = f32_to_bf16(v - bf16_to_f32(hi));
    WH[l * per + n * K + k] = hi;
    WL[l * per + n * K + k] = lo;
}

// ---- h = x @ atom_W + atom_b (f32 vector) ----
__global__ __launch_bounds__(256) void atom_enc(const float* __restrict__ x,
                                                const float* __restrict__ W,
                                                const float* __restrict__ b,
                                                float* __restrict__ h) {
    __shared__ float Wl[IN_DIM * DIM];
    __shared__ float bl[DIM];
    for (int i = threadIdx.x; i < IN_DIM * DIM; i += 256) Wl[i] = W[i];
    if (threadIdx.x < DIM) bl[threadIdx.x] = b[threadIdx.x];
    __syncthreads();
    int col = threadIdx.x & 127;
    int rh  = threadIdx.x >> 7;
    int row0 = blockIdx.x * 32;
    for (int rr = 0; rr < 16; ++rr) {
        int row = row0 + rr * 2 + rh;
        if (row >= N_NODES) return;
        float acc = bl[col];
        const float* xr = x + row * IN_DIM;
        #pragma unroll
        for (int k = 0; k < IN_DIM; k += 4) {
            float4 xv = *(const float4*)(xr + k);
            acc += xv.x * Wl[(k + 0) * DIM + col];
            acc += xv.y * Wl[(k + 1) * DIM + col];
            acc += xv.z * Wl[(k + 2) * DIM + col];
            acc += xv.w * Wl[(k + 3) * DIM + col];
        }
        h[row * DIM + col] = acc;
    }
}

// ---- fused: edge_emb = ea@bW+bb; msg = relu(h[src]+emb); atomic scatter ----
__global__ __launch_bounds__(256) void msg_scatter(const int* __restrict__ ei,
                                                   const float* __restrict__ ea,
                                                   const float* __restrict__ bW,
                                                   const float* __restrict__ bb,
                                                   const float* __restrict__ h,
                                                   float* __restrict__ agg) {
    __shared__ float Wl[13 * DIM];
    __shared__ float bl[DIM];
    for (int i = threadIdx.x; i < 13 * DIM; i += 256) Wl[i] = bW[i];
    if (threadIdx.x < DIM) bl[threadIdx.x] = bb[threadIdx.x];
    __syncthreads();
    int w = threadIdx.x >> 6, lane = threadIdx.x & 63;
    int c0 = lane * 2;
    int e0 = blockIdx.x * 64;
    for (int i = 0; i < 16; ++i) {
        int e = e0 + i * 4 + w;
        int src = ei[e];
        int dst = ei[N_EDGES + e];
        const float* eav = ea + e * 13;
        float ex = bl[c0], ey = bl[c0 + 1];
        #pragma unroll
        for (int k = 0; k < 13; ++k) {
            float a = eav[k];
            ex += a * Wl[k * DIM + c0];
            ey += a * Wl[k * DIM + c0 + 1];
        }
        float2 hv = *(const float2*)(h + src * DIM + c0);
        float mx = fmaxf(hv.x + ex, 0.f);
        float my = fmaxf(hv.y + ey, 0.f);
        atomicAdd(agg + dst * DIM + c0,     mx);
        atomicAdd(agg + dst * DIM + c0 + 1, my);
    }
}

// ---- zf = (1+eps[l])*h + agg (f32) ----
__global__ void z_comp(const float* __restrict__ h, const float* __restrict__ agg,
                       const float* __restrict__ eps, int l, float* __restrict__ zf) {
    int i = blockIdx.x * 256 + threadIdx.x;
    int base = i * 4;
    if (base >= N_NODES * DIM) return;
    float s = 1.0f + eps[l];
    float4 hv = *(const float4*)(h + base);
    float4 av = *(const float4*)(agg + base);
    float4 o;
    o.x = s * hv.x + av.x;
    o.y = s * hv.y + av.y;
    o.z = s * hv.z + av.z;
    o.w = s * hv.w + av.w;
    *(float4*)(zf + base) = o;
}

// ---- split-precision MFMA GEMM: C = A(f32)[M,K] @ BT(split bf16)[NN,K]^T + bias
//      A split to hi/lo bf16 in-register; 3 MFMAs per fragment (hh + lh + hl).
//      Fused per-column sum/sumsq atomics for BN stats. ----
template<int K, int NN>
__global__ __launch_bounds__(256) void gemm_split(const float* __restrict__ A,
                                                  const unsigned short* __restrict__ BH,
                                                  const unsigned short* __restrict__ BL,
                                                  const float* __restrict__ bias,
                                                  float* __restrict__ C,
                                                  float* __restrict__ s,
                                                  float* __restrict__ ss,
                                                  int M) {
    int w = threadIdx.x >> 6, lane = threadIdx.x & 63;
    int rt = blockIdx.x * 4 + w;
    int row0 = rt * 16;
    if (row0 >= M) return;
    int colb = blockIdx.y * 64;
    int lrow = lane & 15;
    int lk   = (lane >> 4) * 8;
    f32x4 acc[4];
    #pragma unroll
    for (int f = 0; f < 4; ++f) acc[f] = (f32x4){0.f, 0.f, 0.f, 0.f};
    const float* Ap = A + (row0 + lrow) * K + lk;
    #pragma unroll
    for (int ks = 0; ks < K / 32; ++ks) {
        float4 a0 = *(const float4*)(Ap + ks * 32);
        float4 a1 = *(const float4*)(Ap + ks * 32 + 4);
        float av0[4] = {a0.x, a0.y, a0.z, a0.w};
        float av1[4] = {a1.x, a1.y, a1.z, a1.w};
        short8 ah, al;
        #pragma unroll
        for (int j = 0; j < 4; ++j) {
            unsigned short hi = f32_to_bf16(av0[j]);
            ah[j] = (short)hi;
            al[j] = (short)f32_to_bf16(av0[j] - bf16_to_f32(hi));
        }
        #pragma unroll
        for (int j = 0; j < 4; ++j) {
            unsigned short hi = f32_to_bf16(av1[j]);
            ah[4 + j] = (short)hi;
            al[4 + j] = (short)f32_to_bf16(av1[j] - bf16_to_f32(hi));
        }
        #pragma unroll
        for (int f = 0; f < 4; ++f) {
            int col = colb + f * 16 + lrow;
            short8 bh = *(const short8*)(BH + col * K + ks * 32 + lk);
            short8 bl = *(const short8*)(BL + col * K + ks * 32 + lk);
            acc[f] = __builtin_amdgcn_mfma_f32_16x16x32_bf16(ah, bh, acc[f], 0, 0, 0);
            acc[f] = __builtin_amdgcn_mfma_f32_16x16x32_bf16(al, bh, acc[f], 0, 0, 0);
            acc[f] = __builtin_amdgcn_mfma_f32_16x16x32_bf16(ah, bl, acc[f], 0, 0, 0);
        }
    }
    int rbase = row0 + (lane >> 4) * 4;
    #pragma unroll
    for (int f = 0; f < 4; ++f) {
        int col = colb + f * 16 + lrow;
        float bv = bias[col];
        float cs = 0.f, css = 0.f;
        #pragma unroll
        for (int r = 0; r < 4; ++r) {
            float v = acc[f][r] + bv;
            C[(rbase + r) * NN + col] = v;
            cs += v;
            css += v * v;
        }
        cs  += __shfl_xor(cs, 16);  css += __shfl_xor(css, 16);
        cs  += __shfl_xor(cs, 32);  css += __shfl_xor(css, 32);
        if ((lane >> 4) == 0) {
            atomicAdd(s + col, cs);
            atomicAdd(ss + col, css);
        }
    }
}

// ---- BN coefficients from sums ----
__global__ void bn_coef(const float* __restrict__ s, const float* __restrict__ ss,
                        const float* __restrict__ g, const float* __restrict__ b,
                        float* __restrict__ a, float* __restrict__ bias, int C) {
    int c = blockIdx.x * blockDim.x + threadIdx.x;
    if (c >= C) return;
    float mu  = s[c] * (1.0f / N_NODES);
    float var = ss[c] * (1.0f / N_NODES) - mu * mu;
    float inv = rsqrtf(var + BN_EPS);
    float av = g[c] * inv;
    a[c] = av;
    bias[c] = b[c] - mu * av;
}

// ---- o = a*z + bias (+relu), f32, generic power-of-2 row width ----
__global__ void bn_apply(const float* __restrict__ z, const float* __restrict__ a,
                         const float* __restrict__ bias, float* __restrict__ o,
                         int total, int nmask, int relu) {
    int i = blockIdx.x * 256 + threadIdx.x;
    int base = i * 4;
    if (base >= total) return;
    int col = base & nmask;
    float4 v = *(const float4*)(z + base);
    float4 r;
    r.x = a[col + 0] * v.x + bias[col + 0];
    r.y = a[col + 1] * v.y + bias[col + 1];
    r.z = a[col + 2] * v.z + bias[col + 2];
    r.w = a[col + 3] * v.w + bias[col + 3];
    if (relu) {
        r.x = fmaxf(r.x, 0.f); r.y = fmaxf(r.y, 0.f);
        r.z = fmaxf(r.z, 0.f); r.w = fmaxf(r.w, 0.f);
    }
    *(float4*)(o + base) = r;
}

extern "C" void kernel_launch(void* const* d_in, const int* in_sizes, int n_in,
                              void* d_out, int out_size, void* d_ws, size_t ws_size,
                              hipStream_t stream) {
    const float* x      = (const float*)d_in[0];
    const int*   ei     = (const int*)d_in[1];
    const float* ea     = (const float*)d_in[2];
    const float* atom_W = (const float*)d_in[3];
    const float* atom_b = (const float*)d_in[4];
    const float* bond_W = (const float*)d_in[5];
    const float* bond_b = (const float*)d_in[6];
    const float* W1     = (const float*)d_in[7];
    const float* b1     = (const float*)d_in[8];
    const float* bn1_g  = (const float*)d_in[9];
    const float* bn1_b  = (const float*)d_in[10];
    const float* W2     = (const float*)d_in[11];
    const float* b2     = (const float*)d_in[12];
    const float* eps    = (const float*)d_in[13];
    const float* bn_g   = (const float*)d_in[14];
    const float* bn_b   = (const float*)d_in[15];
    float* out = (float*)d_out;

    uint8_t* ws = (uint8_t*)d_ws;
    float* h   = (float*)(ws + 0);              // 25,600,000 B
    float* agg = (float*)(ws + 25600000);       // 25,600,000 B (reused as z2)
    float* zf  = (float*)(ws + 51200000);       // 25,600,000 B
    float* y1  = (float*)(ws + 76800000);       // 51,200,000 B
    unsigned short* W1H = (unsigned short*)(ws + 128000000);  // 327,680 B
    unsigned short* W1L = (unsigned short*)(ws + 128327680);
    unsigned short* W2H = (unsigned short*)(ws + 128655360);
    unsigned short* W2L = (unsigned short*)(ws + 128983040);
    float* stats        = (float*)(ws + 129310720);
    float* s1  = stats;        float* ss1 = s1 + 256;
    float* s2  = ss1 + 256;    float* ss2 = s2 + 128;
    float* a1  = ss2 + 128;    float* bb1 = a1 + 256;
    float* a2  = bb1 + 256;    float* bb2 = a2 + 128;
    float* z2  = agg;

    wtrans<<<640, 256, 0, stream>>>(W1, W1H, W1L, 128, 256, LAYERS * 128 * 256);
    wtrans<<<640, 256, 0, stream>>>(W2, W2H, W2L, 256, 128, LAYERS * 256 * 128);

    atom_enc<<<1563, 256, 0, stream>>>(x, atom_W, atom_b, h);

    for (int l = 0; l < LAYERS; ++l) {
        hipMemsetAsync(agg, 0, 25600000, stream);
        hipMemsetAsync(stats, 0, 3072, stream);

        msg_scatter<<<N_EDGES / 64, 256, 0, stream>>>(
            ei, ea, bond_W + l * 13 * DIM, bond_b + l * DIM, h, agg);

        z_comp<<<6250, 256, 0, stream>>>(h, agg, eps, l, zf);

        gemm_split<128, 256><<<dim3(782, 4), 256, 0, stream>>>(
            zf, W1H + l * 256 * 128, W1L + l * 256 * 128, b1 + l * 256, y1, s1, ss1, N_NODES);

        bn_coef<<<1, 256, 0, stream>>>(s1, ss1, bn1_g + l * 256, bn1_b + l * 256, a1, bb1, 256);

        // in-place BN+ReLU on y1
        bn_apply<<<12500, 256, 0, stream>>>(y1, a1, bb1, y1, N_NODES * 256, 255, 1);

        gemm_split<256, 128><<<dim3(782, 2), 256, 0, stream>>>(
            y1, W2H + l * 128 * 256, W2L + l * 128 * 256, b2 + l * 128, z2, s2, ss2, N_NODES);

        bn_coef<<<1, 128, 0, stream>>>(s2, ss2, bn_g + l * 128, bn_b + l * 128, a2, bb2, 128);

        bn_apply<<<6250, 256, 0, stream>>>(
            z2, a2, bb2, (l < LAYERS - 1) ? h : out, N_NODES * DIM, 127, (l < LAYERS - 1) ? 1 : 0);
    }
    (void)in_sizes; (void)n_in; (void)out_size; (void)ws_size;
}

// Round 3
// 2629.728 us; speedup vs baseline: 1.8373x; 1.8373x over previous
//
#include <hip/hip_runtime.h>
#include <stdint.h>

#define N_NODES 50000
#define N_EDGES 640000
#define DIM 128
#define IN_DIM 64
#define LAYERS 5
#define BN_EPS 1e-5f

typedef __attribute__((ext_vector_type(8))) short short8;
typedef __attribute__((ext_vector_type(4))) float f32x4;

__device__ __forceinline__ unsigned short f32_to_bf16(float f) {
    uint32_t u = __float_as_uint(f);
    u += 0x7fffu + ((u >> 16) & 1u);
    return (unsigned short)(u >> 16);
}
__device__ __forceinline__ float bf16_to_f32(unsigned short h) {
    return __uint_as_float(((uint32_t)h) << 16);
}

// ---- weights: W[L][K][NN] -> WT_hi/WT_lo[L][NN][K] (split bf16) ----
__global__ void wtrans(const float* __restrict__ W, unsigned short* __restrict__ WH,
                       unsigned short* __restrict__ WL, int K, int NN, int total) {
    int idx = blockIdx.x * 256 + threadIdx.x;
    if (idx >= total) return;
    int per = K * NN;
    int l = idx / per;
    int r = idx - l * per;
    int k = r / NN;
    int n = r - k * NN;
    float v = W[idx];
    unsigned short hi = f32_to_bf16(v);
    unsigned short lo = f32_to_bf16(v - bf16_to_f32(hi));
    WH[l * per + n * K + k] = hi;
    WL[l * per + n * K + k] = lo;
}

// ---- h = x @ atom_W + atom_b (f32 vector) ----
__global__ __launch_bounds__(256) void atom_enc(const float* __restrict__ x,
                                                const float* __restrict__ W,
                                                const float* __restrict__ b,
                                                float* __restrict__ h) {
    __shared__ float Wl[IN_DIM * DIM];
    __shared__ float bl[DIM];
    for (int i = threadIdx.x; i < IN_DIM * DIM; i += 256) Wl[i] = W[i];
    if (threadIdx.x < DIM) bl[threadIdx.x] = b[threadIdx.x];
    __syncthreads();
    int col = threadIdx.x & 127;
    int rh  = threadIdx.x >> 7;
    int row0 = blockIdx.x * 32;
    for (int rr = 0; rr < 16; ++rr) {
        int row = row0 + rr * 2 + rh;
        if (row >= N_NODES) return;
        float acc = bl[col];
        const float* xr = x + row * IN_DIM;
        #pragma unroll
        for (int k = 0; k < IN_DIM; k += 4) {
            float4 xv = *(const float4*)(xr + k);
            acc += xv.x * Wl[(k + 0) * DIM + col];
            acc += xv.y * Wl[(k + 1) * DIM + col];
            acc += xv.z * Wl[(k + 2) * DIM + col];
            acc += xv.w * Wl[(k + 3) * DIM + col];
        }
        h[row * DIM + col] = acc;
    }
}

// ==== CSR build (once per call, reused for all layers) ====
__global__ void count_deg(const int* __restrict__ ei, int* __restrict__ deg) {
    int e = blockIdx.x * 256 + threadIdx.x;
    if (e < N_EDGES) atomicAdd(&deg[ei[N_EDGES + e]], 1);
}

__global__ __launch_bounds__(1024) void scan_off(const int* __restrict__ deg,
                                                 int* __restrict__ off,
                                                 int* __restrict__ cursor) {
    __shared__ int buf[1024];
    __shared__ int carry_s;
    if (threadIdx.x == 0) carry_s = 0;
    __syncthreads();
    for (int base = 0; base < N_NODES; base += 1024) {
        int i = base + threadIdx.x;
        int v = (i < N_NODES) ? deg[i] : 0;
        buf[threadIdx.x] = v;
        __syncthreads();
        for (int s = 1; s < 1024; s <<= 1) {
            int t = (threadIdx.x >= s) ? buf[threadIdx.x - s] : 0;
            __syncthreads();
            buf[threadIdx.x] += t;
            __syncthreads();
        }
        int carry = carry_s;
        if (i < N_NODES) {
            int excl = carry + buf[threadIdx.x] - v;
            off[i] = excl;
            cursor[i] = excl;
        }
        __syncthreads();
        if (threadIdx.x == 0) carry_s = carry + buf[1023];
        __syncthreads();
    }
    if (threadIdx.x == 0) off[N_NODES] = carry_s;
}

__global__ void fill_csr(const int* __restrict__ ei, int* __restrict__ cursor,
                         int* __restrict__ esrc, int* __restrict__ eidx) {
    int e = blockIdx.x * 256 + threadIdx.x;
    if (e >= N_EDGES) return;
    int dst = ei[N_EDGES + e];
    int pos = atomicAdd(&cursor[dst], 1);
    esrc[pos] = ei[e];
    eidx[pos] = e;
}

// ==== fused per-node aggregation: edge_emb + relu(h[src]+emb) + sum + z ====
// one wave per node; lane owns 2 columns; bond weights in registers.
__global__ __launch_bounds__(256) void agg_csr(const int* __restrict__ off,
                                               const int* __restrict__ esrc,
                                               const int* __restrict__ eidx,
                                               const float* __restrict__ ea,
                                               const float* __restrict__ bW,
                                               const float* __restrict__ bb,
                                               const float* __restrict__ h,
                                               const float* __restrict__ eps,
                                               int l, float* __restrict__ zf) {
    __shared__ float Wl[13 * DIM];
    __shared__ float bl[DIM];
    for (int i = threadIdx.x; i < 13 * DIM; i += 256) Wl[i] = bW[i];
    if (threadIdx.x < DIM) bl[threadIdx.x] = bb[threadIdx.x];
    __syncthreads();
    int w = threadIdx.x >> 6, lane = threadIdx.x & 63;
    int n = blockIdx.x * 4 + w;
    int c0 = lane * 2;
    float w0[13], w1[13];
    #pragma unroll
    for (int k = 0; k < 13; ++k) { w0[k] = Wl[k * DIM + c0]; w1[k] = Wl[k * DIM + c0 + 1]; }
    float b0 = bl[c0], b1v = bl[c0 + 1];
    int e0 = __builtin_amdgcn_readfirstlane(off[n]);
    int e1 = __builtin_amdgcn_readfirstlane(off[n + 1]);
    float ax = 0.f, ay = 0.f;
    for (int s = e0; s < e1; ++s) {
        int src = __builtin_amdgcn_readfirstlane(esrc[s]);
        int eid = __builtin_amdgcn_readfirstlane(eidx[s]);
        const float* eav = ea + (size_t)eid * 13;
        float ex = b0, ey = b1v;
        #pragma unroll
        for (int k = 0; k < 13; ++k) {
            float a = eav[k];
            ex = fmaf(a, w0[k], ex);
            ey = fmaf(a, w1[k], ey);
        }
        float2 hv = *(const float2*)(h + (size_t)src * DIM + c0);
        ax += fmaxf(hv.x + ex, 0.f);
        ay += fmaxf(hv.y + ey, 0.f);
    }
    float sc = 1.0f + eps[l];
    float2 hv = *(const float2*)(h + (size_t)n * DIM + c0);
    float2 o;
    o.x = fmaf(sc, hv.x, ax);
    o.y = fmaf(sc, hv.y, ay);
    *(float2*)(zf + (size_t)n * DIM + c0) = o;
}

// ==== split-precision MFMA GEMM, wave covers full N; optional fused BN+ReLU on A ====
template<int K, int NN, bool FUSE_BN>
__global__ __launch_bounds__(256) void gemm_split(const float* __restrict__ A,
                                                  const unsigned short* __restrict__ BH,
                                                  const unsigned short* __restrict__ BL,
                                                  const float* __restrict__ bias,
                                                  const float* __restrict__ bn_a,
                                                  const float* __restrict__ bn_b,
                                                  float* __restrict__ C,
                                                  float* __restrict__ s,
                                                  float* __restrict__ ss) {
    constexpr int NFRAG = NN / 16;
    int w = threadIdx.x >> 6, lane = threadIdx.x & 63;
    int rt = blockIdx.x * 4 + w;
    int row0 = rt * 16;
    if (row0 >= N_NODES) return;
    int lrow = lane & 15;
    int lk   = (lane >> 4) * 8;
    f32x4 acc[NFRAG];
    #pragma unroll
    for (int f = 0; f < NFRAG; ++f) acc[f] = (f32x4){0.f, 0.f, 0.f, 0.f};
    const float* Ap = A + (size_t)(row0 + lrow) * K + lk;
    #pragma unroll
    for (int ks = 0; ks < K / 32; ++ks) {
        float av[8];
        *(float4*)(av)     = *(const float4*)(Ap + ks * 32);
        *(float4*)(av + 4) = *(const float4*)(Ap + ks * 32 + 4);
        if (FUSE_BN) {
            #pragma unroll
            for (int j = 0; j < 8; ++j) {
                int k = ks * 32 + lk + j;
                av[j] = fmaxf(fmaf(bn_a[k], av[j], bn_b[k]), 0.f);
            }
        }
        short8 ah, al;
        #pragma unroll
        for (int j = 0; j < 8; ++j) {
            unsigned short hi = f32_to_bf16(av[j]);
            ah[j] = (short)hi;
            al[j] = (short)f32_to_bf16(av[j] - bf16_to_f32(hi));
        }
        #pragma unroll
        for (int f = 0; f < NFRAG; ++f) {
            int col = f * 16 + lrow;
            short8 bh  = *(const short8*)(BH + (size_t)col * K + ks * 32 + lk);
            short8 blv = *(const short8*)(BL + (size_t)col * K + ks * 32 + lk);
            acc[f] = __builtin_amdgcn_mfma_f32_16x16x32_bf16(ah, bh,  acc[f], 0, 0, 0);
            acc[f] = __builtin_amdgcn_mfma_f32_16x16x32_bf16(al, bh,  acc[f], 0, 0, 0);
            acc[f] = __builtin_amdgcn_mfma_f32_16x16x32_bf16(ah, blv, acc[f], 0, 0, 0);
        }
    }
    int rbase = row0 + (lane >> 4) * 4;
    #pragma unroll
    for (int f = 0; f < NFRAG; ++f) {
        int col = f * 16 + lrow;
        float bv = bias[col];
        float cs = 0.f, css = 0.f;
        #pragma unroll
        for (int r = 0; r < 4; ++r) {
            float v = acc[f][r] + bv;
            C[(size_t)(rbase + r) * NN + col] = v;
            cs += v;
            css += v * v;
        }
        cs += __shfl_xor(cs, 16);  css += __shfl_xor(css, 16);
        cs += __shfl_xor(cs, 32);  css += __shfl_xor(css, 32);
        if (lane < 16) {
            atomicAdd(s + col, cs);
            atomicAdd(ss + col, css);
        }
    }
}

// ---- BN coefficients from sums ----
__global__ void bn_coef(const float* __restrict__ s, const float* __restrict__ ss,
                        const float* __restrict__ g, const float* __restrict__ b,
                        float* __restrict__ a, float* __restrict__ bias, int C) {
    int c = blockIdx.x * blockDim.x + threadIdx.x;
    if (c >= C) return;
    float mu  = s[c] * (1.0f / N_NODES);
    float var = ss[c] * (1.0f / N_NODES) - mu * mu;
    float inv = rsqrtf(var + BN_EPS);
    float av = g[c] * inv;
    a[c] = av;
    bias[c] = b[c] - mu * av;
}

// ---- o = a*z + bias (+relu), f32 ----
__global__ void bn_apply(const float* __restrict__ z, const float* __restrict__ a,
                         const float* __restrict__ bias, float* __restrict__ o,
                         int total, int nmask, int relu) {
    int i = blockIdx.x * 256 + threadIdx.x;
    int base = i * 4;
    if (base >= total) return;
    int col = base & nmask;
    float4 v = *(const float4*)(z + base);
    float4 r;
    r.x = a[col + 0] * v.x + bias[col + 0];
    r.y = a[col + 1] * v.y + bias[col + 1];
    r.z = a[col + 2] * v.z + bias[col + 2];
    r.w = a[col + 3] * v.w + bias[col + 3];
    if (relu) {
        r.x = fmaxf(r.x, 0.f); r.y = fmaxf(r.y, 0.f);
        r.z = fmaxf(r.z, 0.f); r.w = fmaxf(r.w, 0.f);
    }
    *(float4*)(o + base) = r;
}

extern "C" void kernel_launch(void* const* d_in, const int* in_sizes, int n_in,
                              void* d_out, int out_size, void* d_ws, size_t ws_size,
                              hipStream_t stream) {
    const float* x      = (const float*)d_in[0];
    const int*   ei     = (const int*)d_in[1];
    const float* ea     = (const float*)d_in[2];
    const float* atom_W = (const float*)d_in[3];
    const float* atom_b = (const float*)d_in[4];
    const float* bond_W = (const float*)d_in[5];
    const float* bond_b = (const float*)d_in[6];
    const float* W1     = (const float*)d_in[7];
    const float* b1     = (const float*)d_in[8];
    const float* bn1_g  = (const float*)d_in[9];
    const float* bn1_b  = (const float*)d_in[10];
    const float* W2     = (const float*)d_in[11];
    const float* b2     = (const float*)d_in[12];
    const float* eps    = (const float*)d_in[13];
    const float* bn_g   = (const float*)d_in[14];
    const float* bn_b   = (const float*)d_in[15];
    float* out = (float*)d_out;

    uint8_t* ws = (uint8_t*)d_ws;
    float* h   = (float*)(ws + 0);              // 25,600,000
    float* zf  = (float*)(ws + 25600000);       // 25,600,000 (reused as z2)
    float* y1  = (float*)(ws + 51200000);       // 51,200,000
    unsigned short* W1H = (unsigned short*)(ws + 102400000);  // 327,680 each
    unsigned short* W1L = (unsigned short*)(ws + 102727680);
    unsigned short* W2H = (unsigned short*)(ws + 103055360);
    unsigned short* W2L = (unsigned short*)(ws + 103383040);
    float* stats = (float*)(ws + 103710720);    // 6,144
    int* off     = (int*)(ws + 103716864);      // 200,004
    int* cursor  = (int*)(ws + 103916868);      // 200,004
    int* esrc    = (int*)(ws + 104116872);      // 2,560,000
    int* eidx    = (int*)(ws + 106676872);      // 2,560,000
    int* deg     = (int*)(ws + 109236872);      // 200,000
    float* s1  = stats;        float* ss1 = s1 + 256;
    float* s2  = ss1 + 256;    float* ss2 = s2 + 128;
    float* a1  = ss2 + 128;    float* bb1 = a1 + 256;
    float* a2  = bb1 + 256;    float* bb2 = a2 + 128;
    float* z2  = zf;

    wtrans<<<640, 256, 0, stream>>>(W1, W1H, W1L, 128, 256, LAYERS * 128 * 256);
    wtrans<<<640, 256, 0, stream>>>(W2, W2H, W2L, 256, 128, LAYERS * 256 * 128);

    atom_enc<<<1563, 256, 0, stream>>>(x, atom_W, atom_b, h);

    // CSR build (once, reused across layers)
    hipMemsetAsync(deg, 0, 200000, stream);
    count_deg<<<2500, 256, 0, stream>>>(ei, deg);
    scan_off<<<1, 1024, 0, stream>>>(deg, off, cursor);
    fill_csr<<<2500, 256, 0, stream>>>(ei, cursor, esrc, eidx);

    for (int l = 0; l < LAYERS; ++l) {
        hipMemsetAsync(stats, 0, 3072, stream);

        agg_csr<<<12500, 256, 0, stream>>>(
            off, esrc, eidx, ea, bond_W + l * 13 * DIM, bond_b + l * DIM, h, eps, l, zf);

        gemm_split<128, 256, false><<<782, 256, 0, stream>>>(
            zf, W1H + l * 256 * 128, W1L + l * 256 * 128, b1 + l * 256,
            nullptr, nullptr, y1, s1, ss1);

        bn_coef<<<1, 256, 0, stream>>>(s1, ss1, bn1_g + l * 256, bn1_b + l * 256, a1, bb1, 256);

        gemm_split<256, 128, true><<<782, 256, 0, stream>>>(
            y1, W2H + l * 128 * 256, W2L + l * 128 * 256, b2 + l * 128,
            a1, bb1, z2, s2, ss2);

        bn_coef<<<1, 256, 0, stream>>>(s2, ss2, bn_g + l * 128, bn_b + l * 128, a2, bb2, 128);

        bn_apply<<<6250, 256, 0, stream>>>(
            z2, a2, bb2, (l < LAYERS - 1) ? h : out, N_NODES * DIM, 127, (l < LAYERS - 1) ? 1 : 0);
    }
    (void)in_sizes; (void)n_in; (void)out_size; (void)ws_size;
}

// Round 4
// 1654.300 us; speedup vs baseline: 2.9207x; 1.5896x over previous
//
#include <hip/hip_runtime.h>
#include <stdint.h>

#define N_NODES 50000
#define N_EDGES 640000
#define DIM 128
#define IN_DIM 64
#define LAYERS 5
#define BN_EPS 1e-5f
#define NBLK 782   // M row-tile blocks: 782*4 waves*16 rows >= 50000

typedef __attribute__((ext_vector_type(8))) short short8;
typedef __attribute__((ext_vector_type(4))) float f32x4;

__device__ __forceinline__ unsigned short f32_to_bf16(float f) {
    uint32_t u = __float_as_uint(f);
    u += 0x7fffu + ((u >> 16) & 1u);
    return (unsigned short)(u >> 16);
}
__device__ __forceinline__ float bf16_to_f32(unsigned short h) {
    return __uint_as_float(((uint32_t)h) << 16);
}

// ---- weights: W[L][K][NN] -> WT_hi/WT_lo[L][NN][K] (split bf16) ----
__global__ void wtrans(const float* __restrict__ W, unsigned short* __restrict__ WH,
                       unsigned short* __restrict__ WL, int K, int NN, int total) {
    int idx = blockIdx.x * 256 + threadIdx.x;
    if (idx >= total) return;
    int per = K * NN;
    int l = idx / per;
    int r = idx - l * per;
    int k = r / NN;
    int n = r - k * NN;
    float v = W[idx];
    unsigned short hi = f32_to_bf16(v);
    unsigned short lo = f32_to_bf16(v - bf16_to_f32(hi));
    WH[l * per + n * K + k] = hi;
    WL[l * per + n * K + k] = lo;
}

// ---- h = x @ atom_W + atom_b (f32 vector) ----
__global__ __launch_bounds__(256) void atom_enc(const float* __restrict__ x,
                                                const float* __restrict__ W,
                                                const float* __restrict__ b,
                                                float* __restrict__ h) {
    __shared__ float Wl[IN_DIM * DIM];
    __shared__ float bl[DIM];
    for (int i = threadIdx.x; i < IN_DIM * DIM; i += 256) Wl[i] = W[i];
    if (threadIdx.x < DIM) bl[threadIdx.x] = b[threadIdx.x];
    __syncthreads();
    int col = threadIdx.x & 127;
    int rh  = threadIdx.x >> 7;
    int row0 = blockIdx.x * 32;
    for (int rr = 0; rr < 16; ++rr) {
        int row = row0 + rr * 2 + rh;
        if (row >= N_NODES) return;
        float acc = bl[col];
        const float* xr = x + row * IN_DIM;
        #pragma unroll
        for (int k = 0; k < IN_DIM; k += 4) {
            float4 xv = *(const float4*)(xr + k);
            acc += xv.x * Wl[(k + 0) * DIM + col];
            acc += xv.y * Wl[(k + 1) * DIM + col];
            acc += xv.z * Wl[(k + 2) * DIM + col];
            acc += xv.w * Wl[(k + 3) * DIM + col];
        }
        h[row * DIM + col] = acc;
    }
}

// ==== CSR build ====
__global__ void count_deg(const int* __restrict__ ei, int* __restrict__ deg) {
    int e = blockIdx.x * 256 + threadIdx.x;
    if (e < N_EDGES) atomicAdd(&deg[ei[N_EDGES + e]], 1);
}

__global__ __launch_bounds__(1024) void scan_off(const int* __restrict__ deg,
                                                 int* __restrict__ off,
                                                 int* __restrict__ cursor) {
    __shared__ int wsum[16];
    __shared__ int carry_s;
    int tid = threadIdx.x, w = tid >> 6, lane = tid & 63;
    if (tid == 0) carry_s = 0;
    __syncthreads();
    for (int base = 0; base < N_NODES; base += 1024) {
        int i = base + tid;
        int v = (i < N_NODES) ? deg[i] : 0;
        int x = v;
        #pragma unroll
        for (int d = 1; d < 64; d <<= 1) {
            int t = __shfl_up(x, d);
            if (lane >= d) x += t;
        }
        if (lane == 63) wsum[w] = x;
        __syncthreads();
        if (w == 0) {
            int s_ = (lane < 16) ? wsum[lane] : 0;
            #pragma unroll
            for (int d = 1; d < 16; d <<= 1) {
                int t = __shfl_up(s_, d);
                if (lane >= d) s_ += t;
            }
            if (lane < 16) wsum[lane] = s_;
        }
        __syncthreads();
        int wbase = (w == 0) ? 0 : wsum[w - 1];
        int excl = carry_s + wbase + x - v;
        if (i < N_NODES) { off[i] = excl; cursor[i] = excl; }
        int chunk_total = wsum[15];
        __syncthreads();
        if (tid == 0) carry_s += chunk_total;
        __syncthreads();
    }
    if (threadIdx.x == 0) off[N_NODES] = carry_s;
}

__global__ void fill_csr(const int* __restrict__ ei, int* __restrict__ cursor,
                         int* __restrict__ esrc, int* __restrict__ eidx) {
    int e = blockIdx.x * 256 + threadIdx.x;
    if (e >= N_EDGES) return;
    int dst = ei[N_EDGES + e];
    int pos = atomicAdd(&cursor[dst], 1);
    esrc[pos] = ei[e];
    eidx[pos] = e;
}

// ==== fused per-node aggregation, depth-2 software pipeline ====
// one wave per node; lane owns 2 columns; zf = (1+eps)*h + sum(relu(h[src]+emb))
__global__ __launch_bounds__(256) void agg_csr(const int* __restrict__ off,
                                               const int* __restrict__ esrc,
                                               const int* __restrict__ eidx,
                                               const float* __restrict__ ea,
                                               const float* __restrict__ bW,
                                               const float* __restrict__ bb,
                                               const float* __restrict__ h,
                                               const float* __restrict__ eps,
                                               int l, float* __restrict__ zf) {
    __shared__ float Wl[13 * DIM];
    __shared__ float bl[DIM];
    for (int i = threadIdx.x; i < 13 * DIM; i += 256) Wl[i] = bW[i];
    if (threadIdx.x < DIM) bl[threadIdx.x] = bb[threadIdx.x];
    __syncthreads();
    int w = threadIdx.x >> 6, lane = threadIdx.x & 63;
    int n = blockIdx.x * 4 + w;
    int c0 = lane * 2;
    float w0[13], w1[13];
    #pragma unroll
    for (int k = 0; k < 13; ++k) { w0[k] = Wl[k * DIM + c0]; w1[k] = Wl[k * DIM + c0 + 1]; }
    float b0 = bl[c0], b1v = bl[c0 + 1];
    int e0 = __builtin_amdgcn_readfirstlane(off[n]);
    int e1 = __builtin_amdgcn_readfirstlane(off[n + 1]);
    int deg = e1 - e0;
    int t = e0 + lane;
    int my_src = (t < e1) ? esrc[t] : 0;
    int my_eid = (t < e1) ? eidx[t] : 0;
    int cnt = deg < 64 ? deg : 64;
    float ax = 0.f, ay = 0.f;

    float a_[13]; float2 hv;
    if (cnt > 0) {
        int s_ = __shfl(my_src, 0), e_ = __shfl(my_eid, 0);
        const float* p = ea + (size_t)e_ * 13;
        #pragma unroll
        for (int k = 0; k < 13; ++k) a_[k] = p[k];
        hv = *(const float2*)(h + (size_t)s_ * DIM + c0);
    }
    for (int i = 0; i < cnt; ++i) {
        float nb[13]; float2 nh;
        if (i + 1 < cnt) {
            int s_ = __shfl(my_src, i + 1), e_ = __shfl(my_eid, i + 1);
            const float* p = ea + (size_t)e_ * 13;
            #pragma unroll
            for (int k = 0; k < 13; ++k) nb[k] = p[k];
            nh = *(const float2*)(h + (size_t)s_ * DIM + c0);
        }
        float ex = b0, ey = b1v;
        #pragma unroll
        for (int k = 0; k < 13; ++k) {
            ex = fmaf(a_[k], w0[k], ex);
            ey = fmaf(a_[k], w1[k], ey);
        }
        ax += fmaxf(hv.x + ex, 0.f);
        ay += fmaxf(hv.y + ey, 0.f);
        if (i + 1 < cnt) {
            #pragma unroll
            for (int k = 0; k < 13; ++k) a_[k] = nb[k];
            hv = nh;
        }
    }
    // cold tail for deg > 64 (practically never taken)
    for (int s2 = e0 + 64; s2 < e1; ++s2) {
        int src = __builtin_amdgcn_readfirstlane(esrc[s2]);
        int eid = __builtin_amdgcn_readfirstlane(eidx[s2]);
        const float* p = ea + (size_t)eid * 13;
        float ex = b0, ey = b1v;
        #pragma unroll
        for (int k = 0; k < 13; ++k) {
            float a = p[k];
            ex = fmaf(a, w0[k], ex);
            ey = fmaf(a, w1[k], ey);
        }
        float2 hvv = *(const float2*)(h + (size_t)src * DIM + c0);
        ax += fmaxf(hvv.x + ex, 0.f);
        ay += fmaxf(hvv.y + ey, 0.f);
    }
    float sc = 1.0f + eps[l];
    float2 hn = *(const float2*)(h + (size_t)n * DIM + c0);
    float2 o;
    o.x = fmaf(sc, hn.x, ax);
    o.y = fmaf(sc, hn.y, ay);
    *(float2*)(zf + (size_t)n * DIM + c0) = o;
}

// ==== split-precision MFMA GEMM; grid (NBLK, NN/NC); stats via LDS + partials ====
template<int K, int NN, int NC, bool FUSE_BN>
__global__ __launch_bounds__(256) void gemm_split(const float* __restrict__ A,
                                                  const unsigned short* __restrict__ BH,
                                                  const unsigned short* __restrict__ BL,
                                                  const float* __restrict__ bias,
                                                  const float* __restrict__ bn_a,
                                                  const float* __restrict__ bn_b,
                                                  float* __restrict__ C,
                                                  float* __restrict__ Ps,
                                                  float* __restrict__ Pss) {
    constexpr int NFRAG = NC / 16;
    __shared__ float red[4][2][NC];
    int w = threadIdx.x >> 6, lane = threadIdx.x & 63;
    int rt = blockIdx.x * 4 + w;
    int row0 = rt * 16;
    int gy = blockIdx.y;
    bool active = row0 < N_NODES;
    int lrow = lane & 15;
    int lk   = (lane >> 4) * 8;
    f32x4 acc[NFRAG];
    #pragma unroll
    for (int f = 0; f < NFRAG; ++f) acc[f] = (f32x4){0.f, 0.f, 0.f, 0.f};
    if (active) {
        const float* Ap = A + (size_t)(row0 + lrow) * K + lk;
        #pragma unroll
        for (int ks = 0; ks < K / 32; ++ks) {
            float av[8];
            *(float4*)(av)     = *(const float4*)(Ap + ks * 32);
            *(float4*)(av + 4) = *(const float4*)(Ap + ks * 32 + 4);
            if (FUSE_BN) {
                #pragma unroll
                for (int j = 0; j < 8; ++j) {
                    int k = ks * 32 + lk + j;
                    av[j] = fmaxf(fmaf(bn_a[k], av[j], bn_b[k]), 0.f);
                }
            }
            short8 ah, al;
            #pragma unroll
            for (int j = 0; j < 8; ++j) {
                unsigned short hi = f32_to_bf16(av[j]);
                ah[j] = (short)hi;
                al[j] = (short)f32_to_bf16(av[j] - bf16_to_f32(hi));
            }
            #pragma unroll
            for (int f = 0; f < NFRAG; ++f) {
                int gcol = gy * NC + f * 16 + lrow;
                short8 bh  = *(const short8*)(BH + (size_t)gcol * K + ks * 32 + lk);
                short8 blv = *(const short8*)(BL + (size_t)gcol * K + ks * 32 + lk);
                acc[f] = __builtin_amdgcn_mfma_f32_16x16x32_bf16(ah, bh,  acc[f], 0, 0, 0);
                acc[f] = __builtin_amdgcn_mfma_f32_16x16x32_bf16(al, bh,  acc[f], 0, 0, 0);
                acc[f] = __builtin_amdgcn_mfma_f32_16x16x32_bf16(ah, blv, acc[f], 0, 0, 0);
            }
        }
    }
    int rbase = row0 + (lane >> 4) * 4;
    #pragma unroll
    for (int f = 0; f < NFRAG; ++f) {
        float cs = 0.f, css = 0.f;
        if (active) {
            int gcol = gy * NC + f * 16 + lrow;
            float bv = bias[gcol];
            #pragma unroll
            for (int r = 0; r < 4; ++r) {
                float v = acc[f][r] + bv;
                C[(size_t)(rbase + r) * NN + gcol] = v;
                cs += v;
                css += v * v;
            }
            cs += __shfl_xor(cs, 16);  css += __shfl_xor(css, 16);
            cs += __shfl_xor(cs, 32);  css += __shfl_xor(css, 32);
        }
        if (lane < 16) {
            red[w][0][f * 16 + lrow] = cs;
            red[w][1][f * 16 + lrow] = css;
        }
    }
    __syncthreads();
    int tid = threadIdx.x;
    if (tid < NC) {
        float v = red[0][0][tid] + red[1][0][tid] + red[2][0][tid] + red[3][0][tid];
        Ps[((size_t)gy * NBLK + blockIdx.x) * NC + tid] = v;
    } else if (tid < 2 * NC) {
        int c = tid - NC;
        float v = red[0][1][c] + red[1][1][c] + red[2][1][c] + red[3][1][c];
        Pss[((size_t)gy * NBLK + blockIdx.x) * NC + c] = v;
    }
}

// ---- reduce partials over blocks + compute BN coefficients; one wave per column ----
__global__ void reduce_bn(const float* __restrict__ Ps, const float* __restrict__ Pss,
                          const float* __restrict__ g, const float* __restrict__ bvec,
                          float* __restrict__ a, float* __restrict__ bias,
                          int NC, int C) {
    int w = threadIdx.x >> 6, lane = threadIdx.x & 63;
    int col = blockIdx.x * 4 + w;
    if (col >= C) return;
    int gy = col / NC, lc = col - gy * NC;
    const float* ps  = Ps  + ((size_t)gy * NBLK) * NC + lc;
    const float* pss = Pss + ((size_t)gy * NBLK) * NC + lc;
    float s = 0.f, ss = 0.f;
    for (int b = lane; b < NBLK; b += 64) {
        s  += ps[(size_t)b * NC];
        ss += pss[(size_t)b * NC];
    }
    #pragma unroll
    for (int d = 1; d < 64; d <<= 1) {
        s += __shfl_xor(s, d);
        ss += __shfl_xor(ss, d);
    }
    if (lane == 0) {
        float mu  = s * (1.0f / N_NODES);
        float var = ss * (1.0f / N_NODES) - mu * mu;
        float inv = rsqrtf(var + BN_EPS);
        float av = g[col] * inv;
        a[col] = av;
        bias[col] = bvec[col] - mu * av;
    }
}

// ---- o = a*z + bias (+relu), f32 ----
__global__ void bn_apply(const float* __restrict__ z, const float* __restrict__ a,
                         const float* __restrict__ bias, float* __restrict__ o,
                         int total, int nmask, int relu) {
    int i = blockIdx.x * 256 + threadIdx.x;
    int base = i * 4;
    if (base >= total) return;
    int col = base & nmask;
    float4 v = *(const float4*)(z + base);
    float4 r;
    r.x = a[col + 0] * v.x + bias[col + 0];
    r.y = a[col + 1] * v.y + bias[col + 1];
    r.z = a[col + 2] * v.z + bias[col + 2];
    r.w = a[col + 3] * v.w + bias[col + 3];
    if (relu) {
        r.x = fmaxf(r.x, 0.f); r.y = fmaxf(r.y, 0.f);
        r.z = fmaxf(r.z, 0.f); r.w = fmaxf(r.w, 0.f);
    }
    *(float4*)(o + base) = r;
}

extern "C" void kernel_launch(void* const* d_in, const int* in_sizes, int n_in,
                              void* d_out, int out_size, void* d_ws, size_t ws_size,
                              hipStream_t stream) {
    const float* x      = (const float*)d_in[0];
    const int*   ei     = (const int*)d_in[1];
    const float* ea     = (const float*)d_in[2];
    const float* atom_W = (const float*)d_in[3];
    const float* atom_b = (const float*)d_in[4];
    const float* bond_W = (const float*)d_in[5];
    const float* bond_b = (const float*)d_in[6];
    const float* W1     = (const float*)d_in[7];
    const float* b1     = (const float*)d_in[8];
    const float* bn1_g  = (const float*)d_in[9];
    const float* bn1_b  = (const float*)d_in[10];
    const float* W2     = (const float*)d_in[11];
    const float* b2     = (const float*)d_in[12];
    const float* eps    = (const float*)d_in[13];
    const float* bn_g   = (const float*)d_in[14];
    const float* bn_b   = (const float*)d_in[15];
    float* out = (float*)d_out;

    uint8_t* ws = (uint8_t*)d_ws;
    float* h   = (float*)(ws + 0);              // 25,600,000
    float* zf  = (float*)(ws + 25600000);       // 25,600,000 (also z2)
    float* y1  = (float*)(ws + 51200000);       // 51,200,000
    unsigned short* W1H = (unsigned short*)(ws + 102400000);
    unsigned short* W1L = (unsigned short*)(ws + 102727680);
    unsigned short* W2H = (unsigned short*)(ws + 103055360);
    unsigned short* W2L = (unsigned short*)(ws + 103383040);
    float* coef  = (float*)(ws + 103710720);    // 4,096
    int* off     = (int*)(ws + 103714816);      // 200,064
    int* cursor  = (int*)(ws + 103914880);      // 200,064
    int* esrc    = (int*)(ws + 104114944);      // 2,560,000
    int* eidx    = (int*)(ws + 106674944);      // 2,560,000
    int* deg     = (int*)(ws + 109234944);      // 200,000
    float* Ps1   = (float*)(ws + 109434944);    // 800,768  (4*782*64*4)
    float* Pss1  = (float*)(ws + 110235712);    // 800,768
    float* Ps2   = (float*)(ws + 111036480);    // 400,384  (2*782*64*4)
    float* Pss2  = (float*)(ws + 111436864);    // 400,384
    float* a1  = coef;       float* bb1 = a1 + 256;
    float* a2  = bb1 + 256;  float* bb2 = a2 + 128;
    float* z2  = zf;

    wtrans<<<640, 256, 0, stream>>>(W1, W1H, W1L, 128, 256, LAYERS * 128 * 256);
    wtrans<<<640, 256, 0, stream>>>(W2, W2H, W2L, 256, 128, LAYERS * 256 * 128);

    atom_enc<<<1563, 256, 0, stream>>>(x, atom_W, atom_b, h);

    hipMemsetAsync(deg, 0, 200000, stream);
    count_deg<<<2500, 256, 0, stream>>>(ei, deg);
    scan_off<<<1, 1024, 0, stream>>>(deg, off, cursor);
    fill_csr<<<2500, 256, 0, stream>>>(ei, cursor, esrc, eidx);

    for (int l = 0; l < LAYERS; ++l) {
        agg_csr<<<12500, 256, 0, stream>>>(
            off, esrc, eidx, ea, bond_W + l * 13 * DIM, bond_b + l * DIM, h, eps, l, zf);

        gemm_split<128, 256, 64, false><<<dim3(NBLK, 4), 256, 0, stream>>>(
            zf, W1H + l * 256 * 128, W1L + l * 256 * 128, b1 + l * 256,
            nullptr, nullptr, y1, Ps1, Pss1);

        reduce_bn<<<64, 256, 0, stream>>>(Ps1, Pss1, bn1_g + l * 256, bn1_b + l * 256,
                                          a1, bb1, 64, 256);

        gemm_split<256, 128, 64, true><<<dim3(NBLK, 2), 256, 0, stream>>>(
            y1, W2H + l * 128 * 256, W2L + l * 128 * 256, b2 + l * 128,
            a1, bb1, z2, Ps2, Pss2);

        reduce_bn<<<32, 256, 0, stream>>>(Ps2, Pss2, bn_g + l * 128, bn_b + l * 128,
                                          a2, bb2, 64, 128);

        bn_apply<<<6250, 256, 0, stream>>>(
            z2, a2, bb2, (l < LAYERS - 1) ? h : out, N_NODES * DIM, 127, (l < LAYERS - 1) ? 1 : 0);
    }
    (void)in_sizes; (void)n_in; (void)out_size; (void)ws_size;
}

// Round 6
// 1611.735 us; speedup vs baseline: 2.9978x; 1.0264x over previous
//
#include <hip/hip_runtime.h>
#include <stdint.h>

#define N_NODES 50000
#define N_EDGES 640000
#define DIM 128
#define IN_DIM 64
#define LAYERS 5
#define BN_EPS 1e-5f
#define NBLK 782   // M row-tile blocks: 782*4 waves*16 rows >= 50000

typedef __attribute__((ext_vector_type(8))) short short8;
typedef __attribute__((ext_vector_type(4))) float f32x4;

__device__ __forceinline__ unsigned short f32_to_bf16(float f) {
    uint32_t u = __float_as_uint(f);
    u += 0x7fffu + ((u >> 16) & 1u);
    return (unsigned short)(u >> 16);
}
__device__ __forceinline__ float bf16_to_f32(unsigned short h) {
    return __uint_as_float(((uint32_t)h) << 16);
}

// ---- weights: W[L][K][NN] -> WT_hi/WT_lo[L][NN][K] (split bf16) ----
__global__ void wtrans(const float* __restrict__ W, unsigned short* __restrict__ WH,
                       unsigned short* __restrict__ WL, int K, int NN, int total) {
    int idx = blockIdx.x * 256 + threadIdx.x;
    if (idx >= total) return;
    int per = K * NN;
    int l = idx / per;
    int r = idx - l * per;
    int k = r / NN;
    int n = r - k * NN;
    float v = W[idx];
    unsigned short hi = f32_to_bf16(v);
    unsigned short lo = f32_to_bf16(v - bf16_to_f32(hi));
    WH[l * per + n * K + k] = hi;
    WL[l * per + n * K + k] = lo;
}

// ---- h = x @ atom_W + atom_b (f32 vector) ----
__global__ __launch_bounds__(256) void atom_enc(const float* __restrict__ x,
                                                const float* __restrict__ W,
                                                const float* __restrict__ b,
                                                float* __restrict__ h) {
    __shared__ float Wl[IN_DIM * DIM];
    __shared__ float bl[DIM];
    for (int i = threadIdx.x; i < IN_DIM * DIM; i += 256) Wl[i] = W[i];
    if (threadIdx.x < DIM) bl[threadIdx.x] = b[threadIdx.x];
    __syncthreads();
    int col = threadIdx.x & 127;
    int rh  = threadIdx.x >> 7;
    int row0 = blockIdx.x * 32;
    for (int rr = 0; rr < 16; ++rr) {
        int row = row0 + rr * 2 + rh;
        if (row >= N_NODES) return;
        float acc = bl[col];
        const float* xr = x + row * IN_DIM;
        #pragma unroll
        for (int k = 0; k < IN_DIM; k += 4) {
            float4 xv = *(const float4*)(xr + k);
            acc += xv.x * Wl[(k + 0) * DIM + col];
            acc += xv.y * Wl[(k + 1) * DIM + col];
            acc += xv.z * Wl[(k + 2) * DIM + col];
            acc += xv.w * Wl[(k + 3) * DIM + col];
        }
        h[row * DIM + col] = acc;
    }
}

// ==== CSR build ====
__global__ void count_deg(const int* __restrict__ ei, int* __restrict__ deg) {
    int e = blockIdx.x * 256 + threadIdx.x;
    if (e < N_EDGES) atomicAdd(&deg[ei[N_EDGES + e]], 1);
}

__global__ __launch_bounds__(1024) void scan_off(const int* __restrict__ deg,
                                                 int* __restrict__ off,
                                                 int* __restrict__ cursor) {
    __shared__ int wsum[16];
    __shared__ int carry_s;
    int tid = threadIdx.x, w = tid >> 6, lane = tid & 63;
    if (tid == 0) carry_s = 0;
    __syncthreads();
    for (int base = 0; base < N_NODES; base += 1024) {
        int i = base + tid;
        int v = (i < N_NODES) ? deg[i] : 0;
        int x = v;
        #pragma unroll
        for (int d = 1; d < 64; d <<= 1) {
            int t = __shfl_up(x, d);
            if (lane >= d) x += t;
        }
        if (lane == 63) wsum[w] = x;
        __syncthreads();
        if (w == 0) {
            int s_ = (lane < 16) ? wsum[lane] : 0;
            #pragma unroll
            for (int d = 1; d < 16; d <<= 1) {
                int t = __shfl_up(s_, d);
                if (lane >= d) s_ += t;
            }
            if (lane < 16) wsum[lane] = s_;
        }
        __syncthreads();
        int wbase = (w == 0) ? 0 : wsum[w - 1];
        int excl = carry_s + wbase + x - v;
        if (i < N_NODES) { off[i] = excl; cursor[i] = excl; }
        int chunk_total = wsum[15];
        __syncthreads();
        if (tid == 0) carry_s += chunk_total;
        __syncthreads();
    }
    if (threadIdx.x == 0) off[N_NODES] = carry_s;
}

__global__ void fill_csr(const int* __restrict__ ei, int* __restrict__ cursor,
                         int* __restrict__ esrc, int* __restrict__ eidx) {
    int e = blockIdx.x * 256 + threadIdx.x;
    if (e >= N_EDGES) return;
    int dst = ei[N_EDGES + e];
    int pos = atomicAdd(&cursor[dst], 1);
    esrc[pos] = ei[e];
    eidx[pos] = e;
}

// ==== fused per-node aggregation; uniform scalar loads; split-bf16 output ====
// one wave per node; lane owns 2 cols; z=(1+eps)*h + sum(relu(h[src]+emb)) -> (zh,zl)
__global__ __launch_bounds__(256) void agg_csr(const int* __restrict__ off,
                                               const int* __restrict__ esrc,
                                               const int* __restrict__ eidx,
                                               const float* __restrict__ ea,
                                               const float* __restrict__ bW,
                                               const float* __restrict__ bb,
                                               const float* __restrict__ h,
                                               const float* __restrict__ eps,
                                               int l,
                                               unsigned short* __restrict__ zh,
                                               unsigned short* __restrict__ zl) {
    __shared__ float Wl[13 * DIM];
    __shared__ float bl[DIM];
    for (int i = threadIdx.x; i < 13 * DIM; i += 256) Wl[i] = bW[i];
    if (threadIdx.x < DIM) bl[threadIdx.x] = bb[threadIdx.x];
    __syncthreads();
    int w = threadIdx.x >> 6, lane = threadIdx.x & 63;
    int n = blockIdx.x * 4 + w;
    int c0 = lane * 2;
    float w0[13], w1[13];
    #pragma unroll
    for (int k = 0; k < 13; ++k) { w0[k] = Wl[k * DIM + c0]; w1[k] = Wl[k * DIM + c0 + 1]; }
    float b0 = bl[c0], b1v = bl[c0 + 1];
    int e0 = __builtin_amdgcn_readfirstlane(off[n]);
    int e1 = __builtin_amdgcn_readfirstlane(off[n + 1]);
    int deg = e1 - e0;
    int t = e0 + lane;
    int my_src = (t < e1) ? esrc[t] : 0;
    int my_eid = (t < e1) ? eidx[t] : 0;
    int cnt = deg < 64 ? deg : 64;
    float ax = 0.f, ay = 0.f;

    float a_[13]; float2 hv;
    if (cnt > 0) {
        int s_ = __builtin_amdgcn_readlane(my_src, 0);
        int e_ = __builtin_amdgcn_readlane(my_eid, 0);
        const float* p = ea + e_ * 13;       // uniform -> s_load
        #pragma unroll
        for (int k = 0; k < 13; ++k) a_[k] = p[k];
        hv = *(const float2*)(h + s_ * DIM + c0);
    }
    for (int i = 0; i < cnt; ++i) {
        float nb[13]; float2 nh;
        if (i + 1 < cnt) {
            int s_ = __builtin_amdgcn_readlane(my_src, i + 1);
            int e_ = __builtin_amdgcn_readlane(my_eid, i + 1);
            const float* p = ea + e_ * 13;   // uniform -> s_load
            #pragma unroll
            for (int k = 0; k < 13; ++k) nb[k] = p[k];
            nh = *(const float2*)(h + s_ * DIM + c0);
        }
        float ex = b0, ey = b1v;
        #pragma unroll
        for (int k = 0; k < 13; ++k) {
            ex = fmaf(a_[k], w0[k], ex);
            ey = fmaf(a_[k], w1[k], ey);
        }
        ax += fmaxf(hv.x + ex, 0.f);
        ay += fmaxf(hv.y + ey, 0.f);
        if (i + 1 < cnt) {
            #pragma unroll
            for (int k = 0; k < 13; ++k) a_[k] = nb[k];
            hv = nh;
        }
    }
    // cold tail for deg > 64
    for (int s2 = e0 + 64; s2 < e1; ++s2) {
        int src = __builtin_amdgcn_readfirstlane(esrc[s2]);
        int eid = __builtin_amdgcn_readfirstlane(eidx[s2]);
        const float* p = ea + eid * 13;
        float ex = b0, ey = b1v;
        #pragma unroll
        for (int k = 0; k < 13; ++k) {
            float a = p[k];
            ex = fmaf(a, w0[k], ex);
            ey = fmaf(a, w1[k], ey);
        }
        float2 hvv = *(const float2*)(h + src * DIM + c0);
        ax += fmaxf(hvv.x + ex, 0.f);
        ay += fmaxf(hvv.y + ey, 0.f);
    }
    float sc = 1.0f + eps[l];
    float2 hn = *(const float2*)(h + n * DIM + c0);
    float zx = fmaf(sc, hn.x, ax);
    float zy = fmaf(sc, hn.y, ay);
    unsigned short hx = f32_to_bf16(zx), hy = f32_to_bf16(zy);
    ushort2 hiv, lov;
    hiv.x = hx; hiv.y = hy;
    lov.x = f32_to_bf16(zx - bf16_to_f32(hx));
    lov.y = f32_to_bf16(zy - bf16_to_f32(hy));
    *(ushort2*)(zh + n * DIM + c0) = hiv;
    *(ushort2*)(zl + n * DIM + c0) = lov;
}

// ==== MFMA GEMM on pre-split operands; grid (NBLK, NN/NC); LDS-reduced stats ====
template<int K, int NN, int NC, bool OSPLIT>
__global__ __launch_bounds__(256) void gemm_split(const unsigned short* __restrict__ AH,
                                                  const unsigned short* __restrict__ AL,
                                                  const unsigned short* __restrict__ BH,
                                                  const unsigned short* __restrict__ BL,
                                                  const float* __restrict__ bias,
                                                  float* __restrict__ Cf,
                                                  unsigned short* __restrict__ CH,
                                                  unsigned short* __restrict__ CL,
                                                  float* __restrict__ Ps,
                                                  float* __restrict__ Pss) {
    constexpr int NFRAG = NC / 16;
    __shared__ float red[4][2][NC];
    int w = threadIdx.x >> 6, lane = threadIdx.x & 63;
    int rt = blockIdx.x * 4 + w;
    int row0 = rt * 16;
    int gy = blockIdx.y;
    bool active = row0 < N_NODES;
    int lrow = lane & 15;
    int lk   = (lane >> 4) * 8;
    f32x4 acc[NFRAG];
    #pragma unroll
    for (int f = 0; f < NFRAG; ++f) acc[f] = (f32x4){0.f, 0.f, 0.f, 0.f};
    if (active) {
        int abase = (row0 + lrow) * K + lk;
        #pragma unroll
        for (int ks = 0; ks < K / 32; ++ks) {
            short8 ah = *(const short8*)(AH + abase + ks * 32);
            short8 al = *(const short8*)(AL + abase + ks * 32);
            #pragma unroll
            for (int f = 0; f < NFRAG; ++f) {
                int gcol = gy * NC + f * 16 + lrow;
                short8 bh  = *(const short8*)(BH + gcol * K + ks * 32 + lk);
                short8 blv = *(const short8*)(BL + gcol * K + ks * 32 + lk);
                acc[f] = __builtin_amdgcn_mfma_f32_16x16x32_bf16(ah, bh,  acc[f], 0, 0, 0);
                acc[f] = __builtin_amdgcn_mfma_f32_16x16x32_bf16(al, bh,  acc[f], 0, 0, 0);
                acc[f] = __builtin_amdgcn_mfma_f32_16x16x32_bf16(ah, blv, acc[f], 0, 0, 0);
            }
        }
    }
    int rbase = row0 + (lane >> 4) * 4;
    #pragma unroll
    for (int f = 0; f < NFRAG; ++f) {
        float cs = 0.f, css = 0.f;
        if (active) {
            int gcol = gy * NC + f * 16 + lrow;
            float bv = bias[gcol];
            #pragma unroll
            for (int r = 0; r < 4; ++r) {
                float v = acc[f][r] + bv;
                int idx = (rbase + r) * NN + gcol;
                if (OSPLIT) {
                    unsigned short hi = f32_to_bf16(v);
                    CH[idx] = hi;
                    CL[idx] = f32_to_bf16(v - bf16_to_f32(hi));
                } else {
                    Cf[idx] = v;
                }
                cs += v;
                css += v * v;
            }
            cs += __shfl_xor(cs, 16);  css += __shfl_xor(css, 16);
            cs += __shfl_xor(cs, 32);  css += __shfl_xor(css, 32);
        }
        if (lane < 16) {
            red[w][0][f * 16 + lrow] = cs;
            red[w][1][f * 16 + lrow] = css;
        }
    }
    __syncthreads();
    int tid = threadIdx.x;
    if (tid < NC) {
        float v = red[0][0][tid] + red[1][0][tid] + red[2][0][tid] + red[3][0][tid];
        Ps[(gy * NBLK + blockIdx.x) * NC + tid] = v;
    } else if (tid < 2 * NC) {
        int c = tid - NC;
        float v = red[0][1][c] + red[1][1][c] + red[2][1][c] + red[3][1][c];
        Pss[(gy * NBLK + blockIdx.x) * NC + c] = v;
    }
}

// ---- reduce partials + BN coefficients; one wave per column ----
__global__ void reduce_bn(const float* __restrict__ Ps, const float* __restrict__ Pss,
                          const float* __restrict__ g, const float* __restrict__ bvec,
                          float* __restrict__ a, float* __restrict__ bias,
                          int NC, int C) {
    int w = threadIdx.x >> 6, lane = threadIdx.x & 63;
    int col = blockIdx.x * 4 + w;
    if (col >= C) return;
    int gy = col / NC, lc = col - gy * NC;
    const float* ps  = Ps  + (gy * NBLK) * NC + lc;
    const float* pss = Pss + (gy * NBLK) * NC + lc;
    float s = 0.f, ss = 0.f;
    for (int b = lane; b < NBLK; b += 64) {
        s  += ps[b * NC];
        ss += pss[b * NC];
    }
    #pragma unroll
    for (int d = 1; d < 64; d <<= 1) {
        s += __shfl_xor(s, d);
        ss += __shfl_xor(ss, d);
    }
    if (lane == 0) {
        float mu  = s * (1.0f / N_NODES);
        float var = ss * (1.0f / N_NODES) - mu * mu;
        float inv = rsqrtf(var + BN_EPS);
        float av = g[col] * inv;
        a[col] = av;
        bias[col] = bvec[col] - mu * av;
    }
}

// ---- in-place BN+ReLU on split pair: (hi,lo) <- split(relu(a*(hi+lo)+b)) ----
__global__ void bn_split(unsigned short* __restrict__ yh, unsigned short* __restrict__ yl,
                         const float* __restrict__ a, const float* __restrict__ bias,
                         int total, int nmask) {
    int i = blockIdx.x * 256 + threadIdx.x;
    int base = i * 4;
    if (base >= total) return;
    int col = base & nmask;
    ushort4 hv = *(const ushort4*)(yh + base);
    ushort4 lv = *(const ushort4*)(yl + base);
    float v[4] = {
        bf16_to_f32(hv.x) + bf16_to_f32(lv.x),
        bf16_to_f32(hv.y) + bf16_to_f32(lv.y),
        bf16_to_f32(hv.z) + bf16_to_f32(lv.z),
        bf16_to_f32(hv.w) + bf16_to_f32(lv.w),
    };
    unsigned short ho[4], lo[4];
    #pragma unroll
    for (int j = 0; j < 4; ++j) {
        float r = fmaxf(fmaf(a[col + j], v[j], bias[col + j]), 0.f);
        ho[j] = f32_to_bf16(r);
        lo[j] = f32_to_bf16(r - bf16_to_f32(ho[j]));
    }
    *(ushort4*)(yh + base) = make_ushort4(ho[0], ho[1], ho[2], ho[3]);
    *(ushort4*)(yl + base) = make_ushort4(lo[0], lo[1], lo[2], lo[3]);
}

// ---- o = a*z + bias (+relu), f32 ----
__global__ void bn_apply(const float* __restrict__ z, const float* __restrict__ a,
                         const float* __restrict__ bias, float* __restrict__ o,
                         int total, int nmask, int relu) {
    int i = blockIdx.x * 256 + threadIdx.x;
    int base = i * 4;
    if (base >= total) return;
    int col = base & nmask;
    float4 v = *(const float4*)(z + base);
    float4 r;
    r.x = a[col + 0] * v.x + bias[col + 0];
    r.y = a[col + 1] * v.y + bias[col + 1];
    r.z = a[col + 2] * v.z + bias[col + 2];
    r.w = a[col + 3] * v.w + bias[col + 3];
    if (relu) {
        r.x = fmaxf(r.x, 0.f); r.y = fmaxf(r.y, 0.f);
        r.z = fmaxf(r.z, 0.f); r.w = fmaxf(r.w, 0.f);
    }
    *(float4*)(o + base) = r;
}

extern "C" void kernel_launch(void* const* d_in, const int* in_sizes, int n_in,
                              void* d_out, int out_size, void* d_ws, size_t ws_size,
                              hipStream_t stream) {
    const float* x      = (const float*)d_in[0];
    const int*   ei     = (const int*)d_in[1];
    const float* ea     = (const float*)d_in[2];
    const float* atom_W = (const float*)d_in[3];
    const float* atom_b = (const float*)d_in[4];
    const float* bond_W = (const float*)d_in[5];
    const float* bond_b = (const float*)d_in[6];
    const float* W1     = (const float*)d_in[7];
    const float* b1     = (const float*)d_in[8];
    const float* bn1_g  = (const float*)d_in[9];
    const float* bn1_b  = (const float*)d_in[10];
    const float* W2     = (const float*)d_in[11];
    const float* b2     = (const float*)d_in[12];
    const float* eps    = (const float*)d_in[13];
    const float* bn_g   = (const float*)d_in[14];
    const float* bn_b   = (const float*)d_in[15];
    float* out = (float*)d_out;

    uint8_t* ws = (uint8_t*)d_ws;
    float* h            = (float*)(ws + 0);             // 25,600,000
    unsigned short* zh  = (unsigned short*)(ws + 25600000);   // 12,800,000
    unsigned short* zl  = (unsigned short*)(ws + 38400000);   // 12,800,000
    float* z2           = (float*)(ws + 25600000);      // overlaps zh/zl (disjoint lifetime)
    unsigned short* y1h = (unsigned short*)(ws + 51200000);   // 25,600,000
    unsigned short* y1l = (unsigned short*)(ws + 76800000);   // 25,600,000
    unsigned short* W1H = (unsigned short*)(ws + 102400000);
    unsigned short* W1L = (unsigned short*)(ws + 102727680);
    unsigned short* W2H = (unsigned short*)(ws + 103055360);
    unsigned short* W2L = (unsigned short*)(ws + 103383040);
    float* coef  = (float*)(ws + 103710720);
    int* off     = (int*)(ws + 103714816);
    int* cursor  = (int*)(ws + 103914880);
    int* esrc    = (int*)(ws + 104114944);
    int* eidx    = (int*)(ws + 106674944);
    int* deg     = (int*)(ws + 109234944);
    float* Ps1   = (float*)(ws + 109434944);    // 800,768 (2*782*128*4)
    float* Pss1  = (float*)(ws + 110235712);
    float* Ps2   = (float*)(ws + 111036480);    // 400,384 (1*782*128*4)
    float* Pss2  = (float*)(ws + 111436864);
    float* a1  = coef;       float* bb1 = a1 + 256;
    float* a2  = bb1 + 256;  float* bb2 = a2 + 128;

    wtrans<<<640, 256, 0, stream>>>(W1, W1H, W1L, 128, 256, LAYERS * 128 * 256);
    wtrans<<<640, 256, 0, stream>>>(W2, W2H, W2L, 256, 128, LAYERS * 256 * 128);

    atom_enc<<<1563, 256, 0, stream>>>(x, atom_W, atom_b, h);

    hipMemsetAsync(deg, 0, 200000, stream);
    count_deg<<<2500, 256, 0, stream>>>(ei, deg);
    scan_off<<<1, 1024, 0, stream>>>(deg, off, cursor);
    fill_csr<<<2500, 256, 0, stream>>>(ei, cursor, esrc, eidx);

    for (int l = 0; l < LAYERS; ++l) {
        agg_csr<<<12500, 256, 0, stream>>>(
            off, esrc, eidx, ea, bond_W + l * 13 * DIM, bond_b + l * DIM, h, eps, l, zh, zl);

        gemm_split<128, 256, 128, true><<<dim3(NBLK, 2), 256, 0, stream>>>(
            zh, zl, W1H + l * 256 * 128, W1L + l * 256 * 128, b1 + l * 256,
            nullptr, y1h, y1l, Ps1, Pss1);

        reduce_bn<<<64, 256, 0, stream>>>(Ps1, Pss1, bn1_g + l * 256, bn1_b + l * 256,
                                          a1, bb1, 128, 256);

        bn_split<<<12500, 256, 0, stream>>>(y1h, y1l, a1, bb1, N_NODES * 256, 255);

        gemm_split<256, 128, 128, false><<<dim3(NBLK, 1), 256, 0, stream>>>(
            y1h, y1l, W2H + l * 128 * 256, W2L + l * 128 * 256, b2 + l * 128,
            z2, nullptr, nullptr, Ps2, Pss2);

        reduce_bn<<<32, 256, 0, stream>>>(Ps2, Pss2, bn_g + l * 128, bn_b + l * 128,
                                          a2, bb2, 128, 128);

        bn_apply<<<6250, 256, 0, stream>>>(
            z2, a2, bb2, (l < LAYERS - 1) ? h : out, N_NODES * DIM, 127, (l < LAYERS - 1) ? 1 : 0);
    }
    (void)in_sizes; (void)n_in; (void)out_size; (void)ws_size;
}

// Round 12
// 1585.148 us; speedup vs baseline: 3.0481x; 1.0168x over previous
//
#include <hip/hip_runtime.h>
#include <stdint.h>

#define N_NODES 50000
#define N_EDGES 640000
#define DIM 128
#define IN_DIM 64
#define LAYERS 5
#define BN_EPS 1e-5f
#define NBLK 782   // 782*4 waves*16 rows >= 50000 (50000 = 3125*16 exactly)

typedef __attribute__((ext_vector_type(8))) short short8;
typedef __attribute__((ext_vector_type(4))) float f32x4;

__device__ __forceinline__ unsigned short f32_to_bf16(float f) {
    uint32_t u = __float_as_uint(f);
    u += 0x7fffu + ((u >> 16) & 1u);
    return (unsigned short)(u >> 16);
}
__device__ __forceinline__ float bf16_to_f32(unsigned short h) {
    return __uint_as_float(((uint32_t)h) << 16);
}

// ---- weights: W[L][K][NN] -> WT_hi/WT_lo[L][NN][K] (split bf16) ----
__global__ void wtrans(const float* __restrict__ W, unsigned short* __restrict__ WH,
                       unsigned short* __restrict__ WL, int K, int NN, int total) {
    int idx = blockIdx.x * 256 + threadIdx.x;
    if (idx >= total) return;
    int per = K * NN;
    int l = idx / per;
    int r = idx - l * per;
    int k = r / NN;
    int n = r - k * NN;
    float v = W[idx];
    unsigned short hi = f32_to_bf16(v);
    unsigned short lo = f32_to_bf16(v - bf16_to_f32(hi));
    WH[l * per + n * K + k] = hi;
    WL[l * per + n * K + k] = lo;
}

// ---- h = x @ atom_W + atom_b; also writes bf16 mirror hb ----
__global__ __launch_bounds__(256) void atom_enc(const float* __restrict__ x,
                                                const float* __restrict__ W,
                                                const float* __restrict__ b,
                                                float* __restrict__ h,
                                                unsigned short* __restrict__ hb) {
    __shared__ float Wl[IN_DIM * DIM];
    __shared__ float bl[DIM];
    for (int i = threadIdx.x; i < IN_DIM * DIM; i += 256) Wl[i] = W[i];
    if (threadIdx.x < DIM) bl[threadIdx.x] = b[threadIdx.x];
    __syncthreads();
    int col = threadIdx.x & 127;
    int rh  = threadIdx.x >> 7;
    int row0 = blockIdx.x * 32;
    for (int rr = 0; rr < 16; ++rr) {
        int row = row0 + rr * 2 + rh;
        if (row >= N_NODES) return;
        float acc = bl[col];
        const float* xr = x + row * IN_DIM;
        #pragma unroll
        for (int k = 0; k < IN_DIM; k += 4) {
            float4 xv = *(const float4*)(xr + k);
            acc += xv.x * Wl[(k + 0) * DIM + col];
            acc += xv.y * Wl[(k + 1) * DIM + col];
            acc += xv.z * Wl[(k + 2) * DIM + col];
            acc += xv.w * Wl[(k + 3) * DIM + col];
        }
        h[row * DIM + col] = acc;
        hb[row * DIM + col] = f32_to_bf16(acc);
    }
}

// ==== CSR build ====
__global__ void count_deg(const int* __restrict__ ei, int* __restrict__ deg) {
    int e = blockIdx.x * 256 + threadIdx.x;
    if (e < N_EDGES) atomicAdd(&deg[ei[N_EDGES + e]], 1);
}

__global__ __launch_bounds__(1024) void scan_off(const int* __restrict__ deg,
                                                 int* __restrict__ off,
                                                 int* __restrict__ cursor) {
    __shared__ int wsum[16];
    __shared__ int carry_s;
    int tid = threadIdx.x, w = tid >> 6, lane = tid & 63;
    if (tid == 0) carry_s = 0;
    __syncthreads();
    for (int base = 0; base < N_NODES; base += 1024) {
        int i = base + tid;
        int v = (i < N_NODES) ? deg[i] : 0;
        int x = v;
        #pragma unroll
        for (int d = 1; d < 64; d <<= 1) {
            int t = __shfl_up(x, d);
            if (lane >= d) x += t;
        }
        if (lane == 63) wsum[w] = x;
        __syncthreads();
        if (w == 0) {
            int s_ = (lane < 16) ? wsum[lane] : 0;
            #pragma unroll
            for (int d = 1; d < 16; d <<= 1) {
                int t = __shfl_up(s_, d);
                if (lane >= d) s_ += t;
            }
            if (lane < 16) wsum[lane] = s_;
        }
        __syncthreads();
        int wbase = (w == 0) ? 0 : wsum[w - 1];
        int excl = carry_s + wbase + x - v;
        if (i < N_NODES) { off[i] = excl; cursor[i] = excl; }
        int chunk_total = wsum[15];
        __syncthreads();
        if (tid == 0) carry_s += chunk_total;
        __syncthreads();
    }
    if (threadIdx.x == 0) off[N_NODES] = carry_s;
}

__global__ void fill_csr(const int* __restrict__ ei, int* __restrict__ cursor,
                         int* __restrict__ esrc, int* __restrict__ eidx) {
    int e = blockIdx.x * 256 + threadIdx.x;
    if (e >= N_EDGES) return;
    int dst = ei[N_EDGES + e];
    int pos = atomicAdd(&cursor[dst], 1);
    esrc[pos] = ei[e];
    eidx[pos] = e;
}

// ---- CSR-ordered bf16 edge features: eas[s][14] (13 + pad), 28B rows ----
__global__ void ea_sort(const int* __restrict__ eidx, const float* __restrict__ ea,
                        unsigned short* __restrict__ eas) {
    int s = blockIdx.x * 256 + threadIdx.x;
    if (s >= N_EDGES) return;
    int e = eidx[s];
    const float* p = ea + (size_t)e * 13;
    unsigned short* q = eas + (size_t)s * 14;
    #pragma unroll
    for (int k = 0; k < 13; ++k) q[k] = f32_to_bf16(p[k]);
    q[13] = 0;
}

// ==== fused per-node aggregation; sequential bf16 ea, bf16 h gather, depth-2 dbuf ====
__global__ __launch_bounds__(256) void agg_csr(const int* __restrict__ off,
                                               const int* __restrict__ esrc,
                                               const uint32_t* __restrict__ eas32,
                                               const float* __restrict__ bW,
                                               const float* __restrict__ bb,
                                               const float* __restrict__ h,
                                               const uint32_t* __restrict__ hb32,
                                               const float* __restrict__ eps,
                                               int l,
                                               unsigned short* __restrict__ zh,
                                               unsigned short* __restrict__ zl) {
    __shared__ float Wl[13 * DIM];
    __shared__ float bl[DIM];
    for (int i = threadIdx.x; i < 13 * DIM; i += 256) Wl[i] = bW[i];
    if (threadIdx.x < DIM) bl[threadIdx.x] = bb[threadIdx.x];
    __syncthreads();
    int w = threadIdx.x >> 6, lane = threadIdx.x & 63;
    int n = blockIdx.x * 4 + w;
    int c0 = lane * 2;
    float w0[13], w1[13];
    #pragma unroll
    for (int k = 0; k < 13; ++k) { w0[k] = Wl[k * DIM + c0]; w1[k] = Wl[k * DIM + c0 + 1]; }
    float b0 = bl[c0], b1v = bl[c0 + 1];
    int e0 = __builtin_amdgcn_readfirstlane(off[n]);
    int e1 = __builtin_amdgcn_readfirstlane(off[n + 1]);
    int deg = e1 - e0;
    int t = e0 + lane;
    int my_src = (t < e1) ? esrc[t] : 0;
    int cnt = deg < 64 ? deg : 64;
    float ax = 0.f, ay = 0.f;

    uint32_t eA[7], eB[7];
    uint32_t hA = 0, hB = 0;

    auto LOAD = [&](int i, uint32_t* eD, uint32_t& hD) {
        int s_ = __builtin_amdgcn_readlane(my_src, i);
        const uint32_t* p = eas32 + (size_t)(e0 + i) * 7;   // uniform -> s_load
        #pragma unroll
        for (int k = 0; k < 7; ++k) eD[k] = p[k];
        hD = hb32[s_ * (DIM / 2) + lane];
    };
    auto COMPUTE = [&](const uint32_t* eD, uint32_t hD) {
        float f[13];
        #pragma unroll
        for (int k = 0; k < 6; ++k) {
            f[2 * k]     = __uint_as_float(eD[k] << 16);
            f[2 * k + 1] = __uint_as_float(eD[k] & 0xffff0000u);
        }
        f[12] = __uint_as_float(eD[6] << 16);
        float ex = b0, ey = b1v;
        #pragma unroll
        for (int k = 0; k < 13; ++k) {
            ex = fmaf(f[k], w0[k], ex);
            ey = fmaf(f[k], w1[k], ey);
        }
        float hx = __uint_as_float(hD << 16);
        float hy = __uint_as_float(hD & 0xffff0000u);
        ax += fmaxf(hx + ex, 0.f);
        ay += fmaxf(hy + ey, 0.f);
    };

    if (cnt > 0) LOAD(0, eA, hA);
    for (int i = 0; i < cnt; i += 2) {
        if (i + 1 < cnt) LOAD(i + 1, eB, hB);
        COMPUTE(eA, hA);
        if (i + 2 < cnt) LOAD(i + 2, eA, hA);
        if (i + 1 < cnt) COMPUTE(eB, hB);
    }
    // cold tail for deg > 64
    for (int s2 = e0 + 64; s2 < e1; ++s2) {
        int src = __builtin_amdgcn_readfirstlane(esrc[s2]);
        uint32_t eT[7];
        const uint32_t* p = eas32 + (size_t)s2 * 7;
        #pragma unroll
        for (int k = 0; k < 7; ++k) eT[k] = p[k];
        COMPUTE(eT, hb32[src * (DIM / 2) + lane]);
    }

    float sc = 1.0f + eps[l];
    float2 hn = *(const float2*)(h + (size_t)n * DIM + c0);
    float zx = fmaf(sc, hn.x, ax);
    float zy = fmaf(sc, hn.y, ay);
    unsigned short hx = f32_to_bf16(zx), hy = f32_to_bf16(zy);
    ushort2 hiv, lov;
    hiv.x = hx; hiv.y = hy;
    lov.x = f32_to_bf16(zx - bf16_to_f32(hx));
    lov.y = f32_to_bf16(zy - bf16_to_f32(hy));
    *(ushort2*)(zh + (size_t)n * DIM + c0) = hiv;
    *(ushort2*)(zl + (size_t)n * DIM + c0) = lov;
}

// ==== GEMM1: split-pair A (zh,zl) x split B -> f32 C + column partial stats ====
template<int K, int NN, int NC>
__global__ __launch_bounds__(256) void gemm1_split(const unsigned short* __restrict__ AH,
                                                   const unsigned short* __restrict__ AL,
                                                   const unsigned short* __restrict__ BH,
                                                   const unsigned short* __restrict__ BL,
                                                   const float* __restrict__ bias,
                                                   float* __restrict__ Cf,
                                                   float* __restrict__ Ps,
                                                   float* __restrict__ Pss) {
    constexpr int NFRAG = NC / 16;
    __shared__ float red[4][2][NC];
    int w = threadIdx.x >> 6, lane = threadIdx.x & 63;
    int row0 = (blockIdx.x * 4 + w) * 16;
    int gy = blockIdx.y;
    bool active = row0 < N_NODES;
    int lrow = lane & 15;
    int lk   = (lane >> 4) * 8;
    f32x4 acc[NFRAG];
    #pragma unroll
    for (int f = 0; f < NFRAG; ++f) acc[f] = (f32x4){0.f, 0.f, 0.f, 0.f};
    if (active) {
        int abase = (row0 + lrow) * K + lk;
        #pragma unroll
        for (int ks = 0; ks < K / 32; ++ks) {
            short8 ah = *(const short8*)(AH + abase + ks * 32);
            short8 al = *(const short8*)(AL + abase + ks * 32);
            #pragma unroll
            for (int f = 0; f < NFRAG; ++f) {
                int gcol = gy * NC + f * 16 + lrow;
                short8 bh  = *(const short8*)(BH + (size_t)gcol * K + ks * 32 + lk);
                short8 blv = *(const short8*)(BL + (size_t)gcol * K + ks * 32 + lk);
                acc[f] = __builtin_amdgcn_mfma_f32_16x16x32_bf16(ah, bh,  acc[f], 0, 0, 0);
                acc[f] = __builtin_amdgcn_mfma_f32_16x16x32_bf16(al, bh,  acc[f], 0, 0, 0);
                acc[f] = __builtin_amdgcn_mfma_f32_16x16x32_bf16(ah, blv, acc[f], 0, 0, 0);
            }
        }
    }
    int rbase = row0 + (lane >> 4) * 4;
    #pragma unroll
    for (int f = 0; f < NFRAG; ++f) {
        float cs = 0.f, css = 0.f;
        if (active) {
            int gcol = gy * NC + f * 16 + lrow;
            float bv = bias[gcol];
            #pragma unroll
            for (int r = 0; r < 4; ++r) {
                float v = acc[f][r] + bv;
                Cf[(size_t)(rbase + r) * NN + gcol] = v;
                cs += v;
                css += v * v;
            }
            cs += __shfl_xor(cs, 16);  css += __shfl_xor(css, 16);
            cs += __shfl_xor(cs, 32);  css += __shfl_xor(css, 32);
        }
        if (lane < 16) {
            red[w][0][f * 16 + lrow] = cs;
            red[w][1][f * 16 + lrow] = css;
        }
    }
    __syncthreads();
    int tid = threadIdx.x;
    for (int c = tid; c < NC; c += 256) {
        float v = red[0][0][c] + red[1][0][c] + red[2][0][c] + red[3][0][c];
        Ps[((size_t)gy * NBLK + blockIdx.x) * NC + c] = v;
    }
    for (int c = tid; c < NC; c += 256) {
        float v = red[0][1][c] + red[1][1][c] + red[2][1][c] + red[3][1][c];
        Pss[((size_t)gy * NBLK + blockIdx.x) * NC + c] = v;
    }
}

// ==== GEMM2: f32 A with fused BN+ReLU+split in-register -> f32 C + stats ====
template<int K, int NN, int NC>
__global__ __launch_bounds__(256) void gemm_bn(const float* __restrict__ A,
                                               const unsigned short* __restrict__ BH,
                                               const unsigned short* __restrict__ BL,
                                               const float* __restrict__ bias,
                                               const float* __restrict__ bn_a,
                                               const float* __restrict__ bn_b,
                                               float* __restrict__ Cf,
                                               float* __restrict__ Ps,
                                               float* __restrict__ Pss) {
    constexpr int NFRAG = NC / 16;
    __shared__ float red[4][2][NC];
    int w = threadIdx.x >> 6, lane = threadIdx.x & 63;
    int row0 = (blockIdx.x * 4 + w) * 16;
    int gy = blockIdx.y;
    bool active = row0 < N_NODES;
    int lrow = lane & 15;
    int lk   = (lane >> 4) * 8;
    f32x4 acc[NFRAG];
    #pragma unroll
    for (int f = 0; f < NFRAG; ++f) acc[f] = (f32x4){0.f, 0.f, 0.f, 0.f};
    if (active) {
        const float* Ap = A + (size_t)(row0 + lrow) * K + lk;
        #pragma unroll
        for (int ks = 0; ks < K / 32; ++ks) {
            float av[8];
            *(float4*)(av)     = *(const float4*)(Ap + ks * 32);
            *(float4*)(av + 4) = *(const float4*)(Ap + ks * 32 + 4);
            int k0 = ks * 32 + lk;
            float4 ba0 = *(const float4*)(bn_a + k0);
            float4 ba1 = *(const float4*)(bn_a + k0 + 4);
            float4 bb0 = *(const float4*)(bn_b + k0);
            float4 bb1 = *(const float4*)(bn_b + k0 + 4);
            float aa[8] = {ba0.x, ba0.y, ba0.z, ba0.w, ba1.x, ba1.y, ba1.z, ba1.w};
            float ab[8] = {bb0.x, bb0.y, bb0.z, bb0.w, bb1.x, bb1.y, bb1.z, bb1.w};
            short8 ah, al;
            #pragma unroll
            for (int j = 0; j < 8; ++j) {
                float v = fmaxf(fmaf(aa[j], av[j], ab[j]), 0.f);
                unsigned short hi = f32_to_bf16(v);
                ah[j] = (short)hi;
                al[j] = (short)f32_to_bf16(v - bf16_to_f32(hi));
            }
            #pragma unroll
            for (int f = 0; f < NFRAG; ++f) {
                int gcol = gy * NC + f * 16 + lrow;
                short8 bh  = *(const short8*)(BH + (size_t)gcol * K + ks * 32 + lk);
                short8 blv = *(const short8*)(BL + (size_t)gcol * K + ks * 32 + lk);
                acc[f] = __builtin_amdgcn_mfma_f32_16x16x32_bf16(ah, bh,  acc[f], 0, 0, 0);
                acc[f] = __builtin_amdgcn_mfma_f32_16x16x32_bf16(al, bh,  acc[f], 0, 0, 0);
                acc[f] = __builtin_amdgcn_mfma_f32_16x16x32_bf16(ah, blv, acc[f], 0, 0, 0);
            }
        }
    }
    int rbase = row0 + (lane >> 4) * 4;
    #pragma unroll
    for (int f = 0; f < NFRAG; ++f) {
        float cs = 0.f, css = 0.f;
        if (active) {
            int gcol = gy * NC + f * 16 + lrow;
            float bv = bias[gcol];
            #pragma unroll
            for (int r = 0; r < 4; ++r) {
                float v = acc[f][r] + bv;
                Cf[(size_t)(rbase + r) * NN + gcol] = v;
                cs += v;
                css += v * v;
            }
            cs += __shfl_xor(cs, 16);  css += __shfl_xor(css, 16);
            cs += __shfl_xor(cs, 32);  css += __shfl_xor(css, 32);
        }
        if (lane < 16) {
            red[w][0][f * 16 + lrow] = cs;
            red[w][1][f * 16 + lrow] = css;
        }
    }
    __syncthreads();
    int tid = threadIdx.x;
    for (int c = tid; c < NC; c += 256) {
        float v = red[0][0][c] + red[1][0][c] + red[2][0][c] + red[3][0][c];
        Ps[((size_t)gy * NBLK + blockIdx.x) * NC + c] = v;
    }
    for (int c = tid; c < NC; c += 256) {
        float v = red[0][1][c] + red[1][1][c] + red[2][1][c] + red[3][1][c];
        Pss[((size_t)gy * NBLK + blockIdx.x) * NC + c] = v;
    }
}

// ---- reduce partials + BN coefficients; one wave per column ----
__global__ void reduce_bn(const float* __restrict__ Ps, const float* __restrict__ Pss,
                          const float* __restrict__ g, const float* __restrict__ bvec,
                          float* __restrict__ a, float* __restrict__ bias,
                          int NC, int C) {
    int w = threadIdx.x >> 6, lane = threadIdx.x & 63;
    int col = blockIdx.x * 4 + w;
    if (col >= C) return;
    int gy = col / NC, lc = col - gy * NC;
    const float* ps  = Ps  + ((size_t)gy * NBLK) * NC + lc;
    const float* pss = Pss + ((size_t)gy * NBLK) * NC + lc;
    float s = 0.f, ss = 0.f;
    for (int b = lane; b < NBLK; b += 64) {
        s  += ps[(size_t)b * NC];
        ss += pss[(size_t)b * NC];
    }
    #pragma unroll
    for (int d = 1; d < 64; d <<= 1) {
        s += __shfl_xor(s, d);
        ss += __shfl_xor(ss, d);
    }
    if (lane == 0) {
        float mu  = s * (1.0f / N_NODES);
        float var = ss * (1.0f / N_NODES) - mu * mu;
        float inv = rsqrtf(var + BN_EPS);
        float av = g[col] * inv;
        a[col] = av;
        bias[col] = bvec[col] - mu * av;
    }
}

// ---- o = a*z + bias (+relu), f32; optional bf16 mirror ----
__global__ void bn_apply(const float* __restrict__ z, const float* __restrict__ a,
                         const float* __restrict__ bias, float* __restrict__ o,
                         unsigned short* __restrict__ hbout,
                         int total, int nmask, int relu) {
    int i = blockIdx.x * 256 + threadIdx.x;
    int base = i * 4;
    if (base >= total) return;
    int col = base & nmask;
    float4 v = *(const float4*)(z + base);
    float4 r;
    r.x = a[col + 0] * v.x + bias[col + 0];
    r.y = a[col + 1] * v.y + bias[col + 1];
    r.z = a[col + 2] * v.z + bias[col + 2];
    r.w = a[col + 3] * v.w + bias[col + 3];
    if (relu) {
        r.x = fmaxf(r.x, 0.f); r.y = fmaxf(r.y, 0.f);
        r.z = fmaxf(r.z, 0.f); r.w = fmaxf(r.w, 0.f);
    }
    *(float4*)(o + base) = r;
    if (hbout) {
        ushort4 u;
        u.x = f32_to_bf16(r.x); u.y = f32_to_bf16(r.y);
        u.z = f32_to_bf16(r.z); u.w = f32_to_bf16(r.w);
        *(ushort4*)(hbout + base) = u;
    }
}

extern "C" void kernel_launch(void* const* d_in, const int* in_sizes, int n_in,
                              void* d_out, int out_size, void* d_ws, size_t ws_size,
                              hipStream_t stream) {
    const float* x      = (const float*)d_in[0];
    const int*   ei     = (const int*)d_in[1];
    const float* ea     = (const float*)d_in[2];
    const float* atom_W = (const float*)d_in[3];
    const float* atom_b = (const float*)d_in[4];
    const float* bond_W = (const float*)d_in[5];
    const float* bond_b = (const float*)d_in[6];
    const float* W1     = (const float*)d_in[7];
    const float* b1     = (const float*)d_in[8];
    const float* bn1_g  = (const float*)d_in[9];
    const float* bn1_b  = (const float*)d_in[10];
    const float* W2     = (const float*)d_in[11];
    const float* b2     = (const float*)d_in[12];
    const float* eps    = (const float*)d_in[13];
    const float* bn_g   = (const float*)d_in[14];
    const float* bn_b   = (const float*)d_in[15];
    float* out = (float*)d_out;

    uint8_t* ws = (uint8_t*)d_ws;
    float* h            = (float*)(ws + 0);                    // 25,600,000
    unsigned short* hb  = (unsigned short*)(ws + 25600000);    // 12,800,000
    unsigned short* zh  = (unsigned short*)(ws + 38400000);    // 12,800,000
    unsigned short* zl  = (unsigned short*)(ws + 51200000);    // 12,800,000
    float* z2           = (float*)(ws + 38400000);             // overlaps zh+zl (disjoint lifetime)
    float* y1           = (float*)(ws + 64000000);             // 51,200,000
    unsigned short* eas = (unsigned short*)(ws + 115200000);   // 17,920,000 (640000*14*2)
    unsigned short* W1H = (unsigned short*)(ws + 133120000);   // 327,680 each
    unsigned short* W1L = (unsigned short*)(ws + 133447680);
    unsigned short* W2H = (unsigned short*)(ws + 133775360);
    unsigned short* W2L = (unsigned short*)(ws + 134103040);
    float* coef  = (float*)(ws + 134430720);                   // 4,096
    int* off     = (int*)(ws + 134434816);                     // 200,064
    int* esrc    = (int*)(ws + 134634880);                     // 2,560,000
    float* Ps1   = (float*)(ws + 137194880);                   // 800,768
    float* Pss1  = (float*)(ws + 137995648);                   // 800,768
    float* Ps2   = (float*)(ws + 138796416);                   // 400,384
    float* Pss2  = (float*)(ws + 139196800);                   // 400,384 -> end 139,597,184
    // setup-only buffers overlapping y1 (dead until first gemm1):
    int* cursor  = (int*)(ws + 64000000);                      // 200,064
    int* eidx    = (int*)(ws + 64200064);                      // 2,560,000
    int* deg     = (int*)(ws + 66760064);                      // 200,000
    float* a1  = coef;       float* bb1 = a1 + 256;
    float* a2  = bb1 + 256;  float* bb2 = a2 + 128;

    wtrans<<<640, 256, 0, stream>>>(W1, W1H, W1L, 128, 256, LAYERS * 128 * 256);
    wtrans<<<640, 256, 0, stream>>>(W2, W2H, W2L, 256, 128, LAYERS * 256 * 128);

    atom_enc<<<1563, 256, 0, stream>>>(x, atom_W, atom_b, h, hb);

    hipMemsetAsync(deg, 0, 200000, stream);
    count_deg<<<2500, 256, 0, stream>>>(ei, deg);
    scan_off<<<1, 1024, 0, stream>>>(deg, off, cursor);
    fill_csr<<<2500, 256, 0, stream>>>(ei, cursor, esrc, eidx);
    ea_sort<<<2500, 256, 0, stream>>>(eidx, ea, eas);

    for (int l = 0; l < LAYERS; ++l) {
        agg_csr<<<12500, 256, 0, stream>>>(
            off, esrc, (const uint32_t*)eas, bond_W + l * 13 * DIM, bond_b + l * DIM,
            h, (const uint32_t*)hb, eps, l, zh, zl);

        gemm1_split<128, 256, 256><<<dim3(NBLK, 1), 256, 0, stream>>>(
            zh, zl, W1H + l * 256 * 128, W1L + l * 256 * 128, b1 + l * 256,
            y1, Ps1, Pss1);

        reduce_bn<<<64, 256, 0, stream>>>(Ps1, Pss1, bn1_g + l * 256, bn1_b + l * 256,
                                          a1, bb1, 256, 256);

        gemm_bn<256, 128, 128><<<dim3(NBLK, 1), 256, 0, stream>>>(
            y1, W2H + l * 128 * 256, W2L + l * 128 * 256, b2 + l * 128,
            a1, bb1, z2, Ps2, Pss2);

        reduce_bn<<<32, 256, 0, stream>>>(Ps2, Pss2, bn_g + l * 128, bn_b + l * 128,
                                          a2, bb2, 128, 128);

        int last = (l == LAYERS - 1);
        bn_apply<<<6250, 256, 0, stream>>>(
            z2, a2, bb2, last ? out : h, last ? (unsigned short*)nullptr : hb,
            N_NODES * DIM, 127, last ? 0 : 1);
    }
    (void)in_sizes; (void)n_in; (void)out_size; (void)ws_size;
}

// Round 13
// 1525.928 us; speedup vs baseline: 3.1664x; 1.0388x over previous
//
#include <hip/hip_runtime.h>
#include <stdint.h>

#define N_NODES 50000
#define N_EDGES 640000
#define DIM 128
#define IN_DIM 64
#define LAYERS 5
#define BN_EPS 1e-5f
#define NBLK 782   // 782*4 waves*16 rows >= 50000 (50000 = 3125*16 exactly)

typedef __attribute__((ext_vector_type(8))) short short8;
typedef __attribute__((ext_vector_type(4))) float f32x4;

__device__ __forceinline__ unsigned short f32_to_bf16(float f) {
    uint32_t u = __float_as_uint(f);
    u += 0x7fffu + ((u >> 16) & 1u);
    return (unsigned short)(u >> 16);
}
__device__ __forceinline__ float bf16_to_f32(unsigned short h) {
    return __uint_as_float(((uint32_t)h) << 16);
}

// ---- weights: W[L][K][NN] -> WT_hi/WT_lo[L][NN][K] (split bf16) ----
__global__ void wtrans(const float* __restrict__ W, unsigned short* __restrict__ WH,
                       unsigned short* __restrict__ WL, int K, int NN, int total) {
    int idx = blockIdx.x * 256 + threadIdx.x;
    if (idx >= total) return;
    int per = K * NN;
    int l = idx / per;
    int r = idx - l * per;
    int k = r / NN;
    int n = r - k * NN;
    float v = W[idx];
    unsigned short hi = f32_to_bf16(v);
    unsigned short lo = f32_to_bf16(v - bf16_to_f32(hi));
    WH[l * per + n * K + k] = hi;
    WL[l * per + n * K + k] = lo;
}

// ---- h = x @ atom_W + atom_b; also writes bf16 mirror hb ----
__global__ __launch_bounds__(256) void atom_enc(const float* __restrict__ x,
                                                const float* __restrict__ W,
                                                const float* __restrict__ b,
                                                float* __restrict__ h,
                                                unsigned short* __restrict__ hb) {
    __shared__ float Wl[IN_DIM * DIM];
    __shared__ float bl[DIM];
    for (int i = threadIdx.x; i < IN_DIM * DIM; i += 256) Wl[i] = W[i];
    if (threadIdx.x < DIM) bl[threadIdx.x] = b[threadIdx.x];
    __syncthreads();
    int col = threadIdx.x & 127;
    int rh  = threadIdx.x >> 7;
    int row0 = blockIdx.x * 32;
    for (int rr = 0; rr < 16; ++rr) {
        int row = row0 + rr * 2 + rh;
        if (row >= N_NODES) return;
        float acc = bl[col];
        const float* xr = x + row * IN_DIM;
        #pragma unroll
        for (int k = 0; k < IN_DIM; k += 4) {
            float4 xv = *(const float4*)(xr + k);
            acc += xv.x * Wl[(k + 0) * DIM + col];
            acc += xv.y * Wl[(k + 1) * DIM + col];
            acc += xv.z * Wl[(k + 2) * DIM + col];
            acc += xv.w * Wl[(k + 3) * DIM + col];
        }
        h[row * DIM + col] = acc;
        hb[row * DIM + col] = f32_to_bf16(acc);
    }
}

// ==== CSR build ====
__global__ void count_deg(const int* __restrict__ ei, int* __restrict__ deg) {
    int e = blockIdx.x * 256 + threadIdx.x;
    if (e < N_EDGES) atomicAdd(&deg[ei[N_EDGES + e]], 1);
}

__global__ __launch_bounds__(1024) void scan_off(const int* __restrict__ deg,
                                                 int* __restrict__ off,
                                                 int* __restrict__ cursor) {
    __shared__ int wsum[16];
    __shared__ int carry_s;
    int tid = threadIdx.x, w = tid >> 6, lane = tid & 63;
    if (tid == 0) carry_s = 0;
    __syncthreads();
    for (int base = 0; base < N_NODES; base += 1024) {
        int i = base + tid;
        int v = (i < N_NODES) ? deg[i] : 0;
        int x = v;
        #pragma unroll
        for (int d = 1; d < 64; d <<= 1) {
            int t = __shfl_up(x, d);
            if (lane >= d) x += t;
        }
        if (lane == 63) wsum[w] = x;
        __syncthreads();
        if (w == 0) {
            int s_ = (lane < 16) ? wsum[lane] : 0;
            #pragma unroll
            for (int d = 1; d < 16; d <<= 1) {
                int t = __shfl_up(s_, d);
                if (lane >= d) s_ += t;
            }
            if (lane < 16) wsum[lane] = s_;
        }
        __syncthreads();
        int wbase = (w == 0) ? 0 : wsum[w - 1];
        int excl = carry_s + wbase + x - v;
        if (i < N_NODES) { off[i] = excl; cursor[i] = excl; }
        int chunk_total = wsum[15];
        __syncthreads();
        if (tid == 0) carry_s += chunk_total;
        __syncthreads();
    }
    if (threadIdx.x == 0) off[N_NODES] = carry_s;
}

__global__ void fill_csr(const int* __restrict__ ei, int* __restrict__ cursor,
                         int* __restrict__ esrc, int* __restrict__ eidx) {
    int e = blockIdx.x * 256 + threadIdx.x;
    if (e >= N_EDGES) return;
    int dst = ei[N_EDGES + e];
    int pos = atomicAdd(&cursor[dst], 1);
    esrc[pos] = ei[e];
    eidx[pos] = e;
}

// ---- CSR-ordered bf16 edge features: eas[s][14] (13 + pad), 28B rows ----
__global__ void ea_sort(const int* __restrict__ eidx, const float* __restrict__ ea,
                        unsigned short* __restrict__ eas) {
    int s = blockIdx.x * 256 + threadIdx.x;
    if (s >= N_EDGES) return;
    int e = eidx[s];
    const float* p = ea + (size_t)e * 13;
    unsigned short* q = eas + (size_t)s * 14;
    #pragma unroll
    for (int k = 0; k < 13; ++k) q[k] = f32_to_bf16(p[k]);
    q[13] = 0;
}

// ==== fused per-node aggregation; sequential bf16 ea, bf16 h gather, depth-2 dbuf ====
__global__ __launch_bounds__(256) void agg_csr(const int* __restrict__ off,
                                               const int* __restrict__ esrc,
                                               const uint32_t* __restrict__ eas32,
                                               const float* __restrict__ bW,
                                               const float* __restrict__ bb,
                                               const float* __restrict__ h,
                                               const uint32_t* __restrict__ hb32,
                                               const float* __restrict__ eps,
                                               int l,
                                               unsigned short* __restrict__ zh,
                                               unsigned short* __restrict__ zl) {
    __shared__ float Wl[13 * DIM];
    __shared__ float bl[DIM];
    for (int i = threadIdx.x; i < 13 * DIM; i += 256) Wl[i] = bW[i];
    if (threadIdx.x < DIM) bl[threadIdx.x] = bb[threadIdx.x];
    __syncthreads();
    int w = threadIdx.x >> 6, lane = threadIdx.x & 63;
    int n = blockIdx.x * 4 + w;
    int c0 = lane * 2;
    float w0[13], w1[13];
    #pragma unroll
    for (int k = 0; k < 13; ++k) { w0[k] = Wl[k * DIM + c0]; w1[k] = Wl[k * DIM + c0 + 1]; }
    float b0 = bl[c0], b1v = bl[c0 + 1];
    int e0 = __builtin_amdgcn_readfirstlane(off[n]);
    int e1 = __builtin_amdgcn_readfirstlane(off[n + 1]);
    int deg = e1 - e0;
    int t = e0 + lane;
    int my_src = (t < e1) ? esrc[t] : 0;
    int cnt = deg < 64 ? deg : 64;
    float ax = 0.f, ay = 0.f;

    uint32_t eA[7], eB[7];
    uint32_t hA = 0, hB = 0;

    auto LOAD = [&](int i, uint32_t* eD, uint32_t& hD) {
        int s_ = __builtin_amdgcn_readlane(my_src, i);
        const uint32_t* p = eas32 + (size_t)(e0 + i) * 7;   // uniform -> s_load
        #pragma unroll
        for (int k = 0; k < 7; ++k) eD[k] = p[k];
        hD = hb32[s_ * (DIM / 2) + lane];
    };
    auto COMPUTE = [&](const uint32_t* eD, uint32_t hD) {
        float f[13];
        #pragma unroll
        for (int k = 0; k < 6; ++k) {
            f[2 * k]     = __uint_as_float(eD[k] << 16);
            f[2 * k + 1] = __uint_as_float(eD[k] & 0xffff0000u);
        }
        f[12] = __uint_as_float(eD[6] << 16);
        float ex = b0, ey = b1v;
        #pragma unroll
        for (int k = 0; k < 13; ++k) {
            ex = fmaf(f[k], w0[k], ex);
            ey = fmaf(f[k], w1[k], ey);
        }
        float hx = __uint_as_float(hD << 16);
        float hy = __uint_as_float(hD & 0xffff0000u);
        ax += fmaxf(hx + ex, 0.f);
        ay += fmaxf(hy + ey, 0.f);
    };

    if (cnt > 0) LOAD(0, eA, hA);
    for (int i = 0; i < cnt; i += 2) {
        if (i + 1 < cnt) LOAD(i + 1, eB, hB);
        COMPUTE(eA, hA);
        if (i + 2 < cnt) LOAD(i + 2, eA, hA);
        if (i + 1 < cnt) COMPUTE(eB, hB);
    }
    // cold tail for deg > 64
    for (int s2 = e0 + 64; s2 < e1; ++s2) {
        int src = __builtin_amdgcn_readfirstlane(esrc[s2]);
        uint32_t eT[7];
        const uint32_t* p = eas32 + (size_t)s2 * 7;
        #pragma unroll
        for (int k = 0; k < 7; ++k) eT[k] = p[k];
        COMPUTE(eT, hb32[src * (DIM / 2) + lane]);
    }

    float sc = 1.0f + eps[l];
    float2 hn = *(const float2*)(h + (size_t)n * DIM + c0);
    float zx = fmaf(sc, hn.x, ax);
    float zy = fmaf(sc, hn.y, ay);
    unsigned short hx = f32_to_bf16(zx), hy = f32_to_bf16(zy);
    ushort2 hiv, lov;
    hiv.x = hx; hiv.y = hy;
    lov.x = f32_to_bf16(zx - bf16_to_f32(hx));
    lov.y = f32_to_bf16(zy - bf16_to_f32(hy));
    *(ushort2*)(zh + (size_t)n * DIM + c0) = hiv;
    *(ushort2*)(zl + (size_t)n * DIM + c0) = lov;
}

// ==== GEMM1: split-pair A (zh,zl) x split B -> f32 C + column partial stats ====
template<int K, int NN, int NC>
__global__ __launch_bounds__(256) void gemm1_split(const unsigned short* __restrict__ AH,
                                                   const unsigned short* __restrict__ AL,
                                                   const unsigned short* __restrict__ BH,
                                                   const unsigned short* __restrict__ BL,
                                                   const float* __restrict__ bias,
                                                   float* __restrict__ Cf,
                                                   float* __restrict__ Ps,
                                                   float* __restrict__ Pss) {
    constexpr int NFRAG = NC / 16;
    __shared__ float red[4][2][NC];
    int w = threadIdx.x >> 6, lane = threadIdx.x & 63;
    int row0 = (blockIdx.x * 4 + w) * 16;
    int gy = blockIdx.y;
    bool active = row0 < N_NODES;
    int lrow = lane & 15;
    int lk   = (lane >> 4) * 8;
    f32x4 acc[NFRAG];
    #pragma unroll
    for (int f = 0; f < NFRAG; ++f) acc[f] = (f32x4){0.f, 0.f, 0.f, 0.f};
    if (active) {
        int abase = (row0 + lrow) * K + lk;
        #pragma unroll
        for (int ks = 0; ks < K / 32; ++ks) {
            short8 ah = *(const short8*)(AH + abase + ks * 32);
            short8 al = *(const short8*)(AL + abase + ks * 32);
            #pragma unroll
            for (int f = 0; f < NFRAG; ++f) {
                int gcol = gy * NC + f * 16 + lrow;
                short8 bh  = *(const short8*)(BH + (size_t)gcol * K + ks * 32 + lk);
                short8 blv = *(const short8*)(BL + (size_t)gcol * K + ks * 32 + lk);
                acc[f] = __builtin_amdgcn_mfma_f32_16x16x32_bf16(ah, bh,  acc[f], 0, 0, 0);
                acc[f] = __builtin_amdgcn_mfma_f32_16x16x32_bf16(al, bh,  acc[f], 0, 0, 0);
                acc[f] = __builtin_amdgcn_mfma_f32_16x16x32_bf16(ah, blv, acc[f], 0, 0, 0);
            }
        }
    }
    int rbase = row0 + (lane >> 4) * 4;
    #pragma unroll
    for (int f = 0; f < NFRAG; ++f) {
        float cs = 0.f, css = 0.f;
        if (active) {
            int gcol = gy * NC + f * 16 + lrow;
            float bv = bias[gcol];
            #pragma unroll
            for (int r = 0; r < 4; ++r) {
                float v = acc[f][r] + bv;
                Cf[(size_t)(rbase + r) * NN + gcol] = v;
                cs += v;
                css += v * v;
            }
            cs += __shfl_xor(cs, 16);  css += __shfl_xor(css, 16);
            cs += __shfl_xor(cs, 32);  css += __shfl_xor(css, 32);
        }
        if (lane < 16) {
            red[w][0][f * 16 + lrow] = cs;
            red[w][1][f * 16 + lrow] = css;
        }
    }
    __syncthreads();
    int tid = threadIdx.x;
    for (int c = tid; c < NC; c += 256) {
        float v = red[0][0][c] + red[1][0][c] + red[2][0][c] + red[3][0][c];
        Ps[((size_t)gy * NBLK + blockIdx.x) * NC + c] = v;
    }
    for (int c = tid; c < NC; c += 256) {
        float v = red[0][1][c] + red[1][1][c] + red[2][1][c] + red[3][1][c];
        Pss[((size_t)gy * NBLK + blockIdx.x) * NC + c] = v;
    }
}

// ==== GEMM2: f32 A with fused BN+ReLU+split in-register -> f32 C + stats ====
template<int K, int NN, int NC>
__global__ __launch_bounds__(256) void gemm_bn(const float* __restrict__ A,
                                               const unsigned short* __restrict__ BH,
                                               const unsigned short* __restrict__ BL,
                                               const float* __restrict__ bias,
                                               const float* __restrict__ bn_a,
                                               const float* __restrict__ bn_b,
                                               float* __restrict__ Cf,
                                               float* __restrict__ Ps,
                                               float* __restrict__ Pss) {
    constexpr int NFRAG = NC / 16;
    __shared__ float red[4][2][NC];
    int w = threadIdx.x >> 6, lane = threadIdx.x & 63;
    int row0 = (blockIdx.x * 4 + w) * 16;
    int gy = blockIdx.y;
    bool active = row0 < N_NODES;
    int lrow = lane & 15;
    int lk   = (lane >> 4) * 8;
    f32x4 acc[NFRAG];
    #pragma unroll
    for (int f = 0; f < NFRAG; ++f) acc[f] = (f32x4){0.f, 0.f, 0.f, 0.f};
    if (active) {
        const float* Ap = A + (size_t)(row0 + lrow) * K + lk;
        #pragma unroll
        for (int ks = 0; ks < K / 32; ++ks) {
            float av[8];
            *(float4*)(av)     = *(const float4*)(Ap + ks * 32);
            *(float4*)(av + 4) = *(const float4*)(Ap + ks * 32 + 4);
            int k0 = ks * 32 + lk;
            float4 ba0 = *(const float4*)(bn_a + k0);
            float4 ba1 = *(const float4*)(bn_a + k0 + 4);
            float4 bb0 = *(const float4*)(bn_b + k0);
            float4 bb1 = *(const float4*)(bn_b + k0 + 4);
            float aa[8] = {ba0.x, ba0.y, ba0.z, ba0.w, ba1.x, ba1.y, ba1.z, ba1.w};
            float ab[8] = {bb0.x, bb0.y, bb0.z, bb0.w, bb1.x, bb1.y, bb1.z, bb1.w};
            short8 ah, al;
            #pragma unroll
            for (int j = 0; j < 8; ++j) {
                float v = fmaxf(fmaf(aa[j], av[j], ab[j]), 0.f);
                unsigned short hi = f32_to_bf16(v);
                ah[j] = (short)hi;
                al[j] = (short)f32_to_bf16(v - bf16_to_f32(hi));
            }
            #pragma unroll
            for (int f = 0; f < NFRAG; ++f) {
                int gcol = gy * NC + f * 16 + lrow;
                short8 bh  = *(const short8*)(BH + (size_t)gcol * K + ks * 32 + lk);
                short8 blv = *(const short8*)(BL + (size_t)gcol * K + ks * 32 + lk);
                acc[f] = __builtin_amdgcn_mfma_f32_16x16x32_bf16(ah, bh,  acc[f], 0, 0, 0);
                acc[f] = __builtin_amdgcn_mfma_f32_16x16x32_bf16(al, bh,  acc[f], 0, 0, 0);
                acc[f] = __builtin_amdgcn_mfma_f32_16x16x32_bf16(ah, blv, acc[f], 0, 0, 0);
            }
        }
    }
    int rbase = row0 + (lane >> 4) * 4;
    #pragma unroll
    for (int f = 0; f < NFRAG; ++f) {
        float cs = 0.f, css = 0.f;
        if (active) {
            int gcol = gy * NC + f * 16 + lrow;
            float bv = bias[gcol];
            #pragma unroll
            for (int r = 0; r < 4; ++r) {
                float v = acc[f][r] + bv;
                Cf[(size_t)(rbase + r) * NN + gcol] = v;
                cs += v;
                css += v * v;
            }
            cs += __shfl_xor(cs, 16);  css += __shfl_xor(css, 16);
            cs += __shfl_xor(cs, 32);  css += __shfl_xor(css, 32);
        }
        if (lane < 16) {
            red[w][0][f * 16 + lrow] = cs;
            red[w][1][f * 16 + lrow] = css;
        }
    }
    __syncthreads();
    int tid = threadIdx.x;
    for (int c = tid; c < NC; c += 256) {
        float v = red[0][0][c] + red[1][0][c] + red[2][0][c] + red[3][0][c];
        Ps[((size_t)gy * NBLK + blockIdx.x) * NC + c] = v;
    }
    for (int c = tid; c < NC; c += 256) {
        float v = red[0][1][c] + red[1][1][c] + red[2][1][c] + red[3][1][c];
        Pss[((size_t)gy * NBLK + blockIdx.x) * NC + c] = v;
    }
}

// ---- reduce partials + BN coefficients; one wave per column ----
__global__ void reduce_bn(const float* __restrict__ Ps, const float* __restrict__ Pss,
                          const float* __restrict__ g, const float* __restrict__ bvec,
                          float* __restrict__ a, float* __restrict__ bias,
                          int NC, int C) {
    int w = threadIdx.x >> 6, lane = threadIdx.x & 63;
    int col = blockIdx.x * 4 + w;
    if (col >= C) return;
    int gy = col / NC, lc = col - gy * NC;
    const float* ps  = Ps  + ((size_t)gy * NBLK) * NC + lc;
    const float* pss = Pss + ((size_t)gy * NBLK) * NC + lc;
    float s = 0.f, ss = 0.f;
    for (int b = lane; b < NBLK; b += 64) {
        s  += ps[(size_t)b * NC];
        ss += pss[(size_t)b * NC];
    }
    #pragma unroll
    for (int d = 1; d < 64; d <<= 1) {
        s += __shfl_xor(s, d);
        ss += __shfl_xor(ss, d);
    }
    if (lane == 0) {
        float mu  = s * (1.0f / N_NODES);
        float var = ss * (1.0f / N_NODES) - mu * mu;
        float inv = rsqrtf(var + BN_EPS);
        float av = g[col] * inv;
        a[col] = av;
        bias[col] = bvec[col] - mu * av;
    }
}

// ---- o = a*z + bias (+relu), f32; optional bf16 mirror ----
__global__ void bn_apply(const float* __restrict__ z, const float* __restrict__ a,
                         const float* __restrict__ bias, float* __restrict__ o,
                         unsigned short* __restrict__ hbout,
                         int total, int nmask, int relu) {
    int i = blockIdx.x * 256 + threadIdx.x;
    int base = i * 4;
    if (base >= total) return;
    int col = base & nmask;
    float4 v = *(const float4*)(z + base);
    float4 r;
    r.x = a[col + 0] * v.x + bias[col + 0];
    r.y = a[col + 1] * v.y + bias[col + 1];
    r.z = a[col + 2] * v.z + bias[col + 2];
    r.w = a[col + 3] * v.w + bias[col + 3];
    if (relu) {
        r.x = fmaxf(r.x, 0.f); r.y = fmaxf(r.y, 0.f);
        r.z = fmaxf(r.z, 0.f); r.w = fmaxf(r.w, 0.f);
    }
    *(float4*)(o + base) = r;
    if (hbout) {
        ushort4 u;
        u.x = f32_to_bf16(r.x); u.y = f32_to_bf16(r.y);
        u.z = f32_to_bf16(r.z); u.w = f32_to_bf16(r.w);
        *(ushort4*)(hbout + base) = u;
    }
}

extern "C" void kernel_launch(void* const* d_in, const int* in_sizes, int n_in,
                              void* d_out, int out_size, void* d_ws, size_t ws_size,
                              hipStream_t stream) {
    const float* x      = (const float*)d_in[0];
    const int*   ei     = (const int*)d_in[1];
    const float* ea     = (const float*)d_in[2];
    const float* atom_W = (const float*)d_in[3];
    const float* atom_b = (const float*)d_in[4];
    const float* bond_W = (const float*)d_in[5];
    const float* bond_b = (const float*)d_in[6];
    const float* W1     = (const float*)d_in[7];
    const float* b1     = (const float*)d_in[8];
    const float* bn1_g  = (const float*)d_in[9];
    const float* bn1_b  = (const float*)d_in[10];
    const float* W2     = (const float*)d_in[11];
    const float* b2     = (const float*)d_in[12];
    const float* eps    = (const float*)d_in[13];
    const float* bn_g   = (const float*)d_in[14];
    const float* bn_b   = (const float*)d_in[15];
    float* out = (float*)d_out;

    uint8_t* ws = (uint8_t*)d_ws;
    float* h            = (float*)(ws + 0);                    // 25,600,000
    unsigned short* hb  = (unsigned short*)(ws + 25600000);    // 12,800,000
    unsigned short* zh  = (unsigned short*)(ws + 38400000);    // 12,800,000
    unsigned short* zl  = (unsigned short*)(ws + 51200000);    // 12,800,000
    float* z2           = (float*)(ws + 38400000);             // overlaps zh+zl (disjoint lifetime)
    float* y1           = (float*)(ws + 64000000);             // 51,200,000
    unsigned short* eas = (unsigned short*)(ws + 115200000);   // 17,920,000 (640000*14*2)
    unsigned short* W1H = (unsigned short*)(ws + 133120000);   // 327,680 each
    unsigned short* W1L = (unsigned short*)(ws + 133447680);
    unsigned short* W2H = (unsigned short*)(ws + 133775360);
    unsigned short* W2L = (unsigned short*)(ws + 134103040);
    float* coef  = (float*)(ws + 134430720);                   // 4,096
    int* off     = (int*)(ws + 134434816);                     // 200,064
    int* esrc    = (int*)(ws + 134634880);                     // 2,560,000
    float* Ps1   = (float*)(ws + 137194880);                   // 800,768 (4*782*64*4)
    float* Pss1  = (float*)(ws + 137995648);                   // 800,768
    float* Ps2   = (float*)(ws + 138796416);                   // 400,384 (4*782*32*4)
    float* Pss2  = (float*)(ws + 139196800);                   // 400,384 -> end 139,597,184
    // setup-only buffers overlapping y1 (dead until first gemm1):
    int* cursor  = (int*)(ws + 64000000);                      // 200,064
    int* eidx    = (int*)(ws + 64200064);                      // 2,560,000
    int* deg     = (int*)(ws + 66760064);                      // 200,000
    float* a1  = coef;       float* bb1 = a1 + 256;
    float* a2  = bb1 + 256;  float* bb2 = a2 + 128;

    wtrans<<<640, 256, 0, stream>>>(W1, W1H, W1L, 128, 256, LAYERS * 128 * 256);
    wtrans<<<640, 256, 0, stream>>>(W2, W2H, W2L, 256, 128, LAYERS * 256 * 128);

    atom_enc<<<1563, 256, 0, stream>>>(x, atom_W, atom_b, h, hb);

    hipMemsetAsync(deg, 0, 200000, stream);
    count_deg<<<2500, 256, 0, stream>>>(ei, deg);
    scan_off<<<1, 1024, 0, stream>>>(deg, off, cursor);
    fill_csr<<<2500, 256, 0, stream>>>(ei, cursor, esrc, eidx);
    ea_sort<<<2500, 256, 0, stream>>>(eidx, ea, eas);

    for (int l = 0; l < LAYERS; ++l) {
        agg_csr<<<12500, 256, 0, stream>>>(
            off, esrc, (const uint32_t*)eas, bond_W + l * 13 * DIM, bond_b + l * DIM,
            h, (const uint32_t*)hb, eps, l, zh, zl);

        gemm1_split<128, 256, 64><<<dim3(NBLK, 4), 256, 0, stream>>>(
            zh, zl, W1H + l * 256 * 128, W1L + l * 256 * 128, b1 + l * 256,
            y1, Ps1, Pss1);

        reduce_bn<<<64, 256, 0, stream>>>(Ps1, Pss1, bn1_g + l * 256, bn1_b + l * 256,
                                          a1, bb1, 64, 256);

        gemm_bn<256, 128, 32><<<dim3(NBLK, 4), 256, 0, stream>>>(
            y1, W2H + l * 128 * 256, W2L + l * 128 * 256, b2 + l * 128,
            a1, bb1, z2, Ps2, Pss2);

        reduce_bn<<<32, 256, 0, stream>>>(Ps2, Pss2, bn_g + l * 128, bn_b + l * 128,
                                          a2, bb2, 32, 128);

        int last = (l == LAYERS - 1);
        bn_apply<<<6250, 256, 0, stream>>>(
            z2, a2, bb2, last ? out : h, last ? (unsigned short*)nullptr : hb,
            N_NODES * DIM, 127, last ? 0 : 1);
    }
    (void)in_sizes; (void)n_in; (void)out_size; (void)ws_size;
}

// Round 14
// 1519.863 us; speedup vs baseline: 3.1790x; 1.0040x over previous
//
#include <hip/hip_runtime.h>
#include <stdint.h>

#define N_NODES 50000
#define N_EDGES 640000
#define DIM 128
#define IN_DIM 64
#define LAYERS 5
#define BN_EPS 1e-5f
#define NBLK 782   // 782*4 waves*16 rows >= 50000

typedef __attribute__((ext_vector_type(8))) short short8;
typedef __attribute__((ext_vector_type(4))) float f32x4;

__device__ __forceinline__ unsigned short f32_to_bf16(float f) {
    uint32_t u = __float_as_uint(f);
    u += 0x7fffu + ((u >> 16) & 1u);
    return (unsigned short)(u >> 16);
}
__device__ __forceinline__ float bf16_to_f32(unsigned short h) {
    return __uint_as_float(((uint32_t)h) << 16);
}

// ---- weights: W[L][K][NN] -> WT_hi/WT_lo[L][NN][K] (split bf16) ----
__global__ void wtrans(const float* __restrict__ W, unsigned short* __restrict__ WH,
                       unsigned short* __restrict__ WL, int K, int NN, int total) {
    int idx = blockIdx.x * 256 + threadIdx.x;
    if (idx >= total) return;
    int per = K * NN;
    int l = idx / per;
    int r = idx - l * per;
    int k = r / NN;
    int n = r - k * NN;
    float v = W[idx];
    unsigned short hi = f32_to_bf16(v);
    unsigned short lo = f32_to_bf16(v - bf16_to_f32(hi));
    WH[l * per + n * K + k] = hi;
    WL[l * per + n * K + k] = lo;
}

// ---- h = x @ atom_W + atom_b; also writes bf16 mirror hb ----
__global__ __launch_bounds__(256) void atom_enc(const float* __restrict__ x,
                                                const float* __restrict__ W,
                                                const float* __restrict__ b,
                                                float* __restrict__ h,
                                                unsigned short* __restrict__ hb) {
    __shared__ float Wl[IN_DIM * DIM];
    __shared__ float bl[DIM];
    for (int i = threadIdx.x; i < IN_DIM * DIM; i += 256) Wl[i] = W[i];
    if (threadIdx.x < DIM) bl[threadIdx.x] = b[threadIdx.x];
    __syncthreads();
    int col = threadIdx.x & 127;
    int rh  = threadIdx.x >> 7;
    int row0 = blockIdx.x * 32;
    for (int rr = 0; rr < 16; ++rr) {
        int row = row0 + rr * 2 + rh;
        if (row >= N_NODES) return;
        float acc = bl[col];
        const float* xr = x + row * IN_DIM;
        #pragma unroll
        for (int k = 0; k < IN_DIM; k += 4) {
            float4 xv = *(const float4*)(xr + k);
            acc += xv.x * Wl[(k + 0) * DIM + col];
            acc += xv.y * Wl[(k + 1) * DIM + col];
            acc += xv.z * Wl[(k + 2) * DIM + col];
            acc += xv.w * Wl[(k + 3) * DIM + col];
        }
        h[row * DIM + col] = acc;
        hb[row * DIM + col] = f32_to_bf16(acc);
    }
}

// ==== CSR build ====
__global__ void count_deg(const int* __restrict__ ei, int* __restrict__ deg) {
    int e = blockIdx.x * 256 + threadIdx.x;
    if (e < N_EDGES) atomicAdd(&deg[ei[N_EDGES + e]], 1);
}

__global__ __launch_bounds__(1024) void scan_off(const int* __restrict__ deg,
                                                 int* __restrict__ off,
                                                 int* __restrict__ cursor) {
    __shared__ int wsum[16];
    __shared__ int carry_s;
    int tid = threadIdx.x, w = tid >> 6, lane = tid & 63;
    if (tid == 0) carry_s = 0;
    __syncthreads();
    for (int base = 0; base < N_NODES; base += 1024) {
        int i = base + tid;
        int v = (i < N_NODES) ? deg[i] : 0;
        int x = v;
        #pragma unroll
        for (int d = 1; d < 64; d <<= 1) {
            int t = __shfl_up(x, d);
            if (lane >= d) x += t;
        }
        if (lane == 63) wsum[w] = x;
        __syncthreads();
        if (w == 0) {
            int s_ = (lane < 16) ? wsum[lane] : 0;
            #pragma unroll
            for (int d = 1; d < 16; d <<= 1) {
                int t = __shfl_up(s_, d);
                if (lane >= d) s_ += t;
            }
            if (lane < 16) wsum[lane] = s_;
        }
        __syncthreads();
        int wbase = (w == 0) ? 0 : wsum[w - 1];
        int excl = carry_s + wbase + x - v;
        if (i < N_NODES) { off[i] = excl; cursor[i] = excl; }
        int chunk_total = wsum[15];
        __syncthreads();
        if (tid == 0) carry_s += chunk_total;
        __syncthreads();
    }
    if (threadIdx.x == 0) off[N_NODES] = carry_s;
}

__global__ void fill_csr(const int* __restrict__ ei, int* __restrict__ cursor,
                         int* __restrict__ esrc, int* __restrict__ eidx) {
    int e = blockIdx.x * 256 + threadIdx.x;
    if (e >= N_EDGES) return;
    int dst = ei[N_EDGES + e];
    int pos = atomicAdd(&cursor[dst], 1);
    esrc[pos] = ei[e];
    eidx[pos] = e;
}

// ---- CSR-ordered bf16 edge features: eas[s][14] (13 + pad), 28B rows ----
__global__ void ea_sort(const int* __restrict__ eidx, const float* __restrict__ ea,
                        unsigned short* __restrict__ eas) {
    int s = blockIdx.x * 256 + threadIdx.x;
    if (s >= N_EDGES) return;
    int e = eidx[s];
    const float* p = ea + (size_t)e * 13;
    unsigned short* q = eas + (size_t)s * 14;
    #pragma unroll
    for (int k = 0; k < 13; ++k) q[k] = f32_to_bf16(p[k]);
    q[13] = 0;
}

// ==== fused per-node aggregation; sequential bf16 ea, bf16 h gather, depth-2 dbuf ====
__global__ __launch_bounds__(256) void agg_csr(const int* __restrict__ off,
                                               const int* __restrict__ esrc,
                                               const uint32_t* __restrict__ eas32,
                                               const float* __restrict__ bW,
                                               const float* __restrict__ bb,
                                               const float* __restrict__ h,
                                               const uint32_t* __restrict__ hb32,
                                               const float* __restrict__ eps,
                                               int l,
                                               unsigned short* __restrict__ zh,
                                               unsigned short* __restrict__ zl) {
    __shared__ float Wl[13 * DIM];
    __shared__ float bl[DIM];
    for (int i = threadIdx.x; i < 13 * DIM; i += 256) Wl[i] = bW[i];
    if (threadIdx.x < DIM) bl[threadIdx.x] = bb[threadIdx.x];
    __syncthreads();
    int w = threadIdx.x >> 6, lane = threadIdx.x & 63;
    int n = blockIdx.x * 4 + w;
    int c0 = lane * 2;
    float w0[13], w1[13];
    #pragma unroll
    for (int k = 0; k < 13; ++k) { w0[k] = Wl[k * DIM + c0]; w1[k] = Wl[k * DIM + c0 + 1]; }
    float b0 = bl[c0], b1v = bl[c0 + 1];
    int e0 = __builtin_amdgcn_readfirstlane(off[n]);
    int e1 = __builtin_amdgcn_readfirstlane(off[n + 1]);
    int deg = e1 - e0;
    int t = e0 + lane;
    int my_src = (t < e1) ? esrc[t] : 0;
    int cnt = deg < 64 ? deg : 64;
    float ax = 0.f, ay = 0.f;

    uint32_t eA[7], eB[7];
    uint32_t hA = 0, hB = 0;

    auto LOAD = [&](int i, uint32_t* eD, uint32_t& hD) {
        int s_ = __builtin_amdgcn_readlane(my_src, i);
        const uint32_t* p = eas32 + (size_t)(e0 + i) * 7;   // uniform -> s_load
        #pragma unroll
        for (int k = 0; k < 7; ++k) eD[k] = p[k];
        hD = hb32[s_ * (DIM / 2) + lane];
    };
    auto COMPUTE = [&](const uint32_t* eD, uint32_t hD) {
        float f[13];
        #pragma unroll
        for (int k = 0; k < 6; ++k) {
            f[2 * k]     = __uint_as_float(eD[k] << 16);
            f[2 * k + 1] = __uint_as_float(eD[k] & 0xffff0000u);
        }
        f[12] = __uint_as_float(eD[6] << 16);
        float ex = b0, ey = b1v;
        #pragma unroll
        for (int k = 0; k < 13; ++k) {
            ex = fmaf(f[k], w0[k], ex);
            ey = fmaf(f[k], w1[k], ey);
        }
        float hx = __uint_as_float(hD << 16);
        float hy = __uint_as_float(hD & 0xffff0000u);
        ax += fmaxf(hx + ex, 0.f);
        ay += fmaxf(hy + ey, 0.f);
    };

    if (cnt > 0) LOAD(0, eA, hA);
    for (int i = 0; i < cnt; i += 2) {
        if (i + 1 < cnt) LOAD(i + 1, eB, hB);
        COMPUTE(eA, hA);
        if (i + 2 < cnt) LOAD(i + 2, eA, hA);
        if (i + 1 < cnt) COMPUTE(eB, hB);
    }
    // cold tail for deg > 64
    for (int s2 = e0 + 64; s2 < e1; ++s2) {
        int src = __builtin_amdgcn_readfirstlane(esrc[s2]);
        uint32_t eT[7];
        const uint32_t* p = eas32 + (size_t)s2 * 7;
        #pragma unroll
        for (int k = 0; k < 7; ++k) eT[k] = p[k];
        COMPUTE(eT, hb32[src * (DIM / 2) + lane]);
    }

    float sc = 1.0f + eps[l];
    float2 hn = *(const float2*)(h + (size_t)n * DIM + c0);
    float zx = fmaf(sc, hn.x, ax);
    float zy = fmaf(sc, hn.y, ay);
    unsigned short hx = f32_to_bf16(zx), hy = f32_to_bf16(zy);
    ushort2 hiv, lov;
    hiv.x = hx; hiv.y = hy;
    lov.x = f32_to_bf16(zx - bf16_to_f32(hx));
    lov.y = f32_to_bf16(zy - bf16_to_f32(hy));
    *(ushort2*)(zh + (size_t)n * DIM + c0) = hiv;
    *(ushort2*)(zl + (size_t)n * DIM + c0) = lov;
}

// ==== GEMM1: split-pair A front-loaded into registers, then MFMA ====
template<int K, int NN, int NC>
__global__ __launch_bounds__(256) void gemm1_split(const unsigned short* __restrict__ AH,
                                                   const unsigned short* __restrict__ AL,
                                                   const unsigned short* __restrict__ BH,
                                                   const unsigned short* __restrict__ BL,
                                                   const float* __restrict__ bias,
                                                   float* __restrict__ Cf,
                                                   float* __restrict__ Ps,
                                                   float* __restrict__ Pss) {
    constexpr int NFRAG = NC / 16;
    constexpr int KS = K / 32;
    __shared__ float red[4][2][NC];
    int w = threadIdx.x >> 6, lane = threadIdx.x & 63;
    int row0 = (blockIdx.x * 4 + w) * 16;
    int gy = blockIdx.y;
    bool active = row0 < N_NODES;
    int lrow = lane & 15;
    int lk   = (lane >> 4) * 8;
    f32x4 acc[NFRAG];
    #pragma unroll
    for (int f = 0; f < NFRAG; ++f) acc[f] = (f32x4){0.f, 0.f, 0.f, 0.f};
    if (active) {
        int abase = (row0 + lrow) * K + lk;
        // front-load ALL A fragments (2*KS independent loads in flight)
        short8 ahv[KS], alv[KS];
        #pragma unroll
        for (int ks = 0; ks < KS; ++ks) {
            ahv[ks] = *(const short8*)(AH + abase + ks * 32);
            alv[ks] = *(const short8*)(AL + abase + ks * 32);
        }
        #pragma unroll
        for (int f = 0; f < NFRAG; ++f) {
            int gcol = gy * NC + f * 16 + lrow;
            #pragma unroll
            for (int ks = 0; ks < KS; ++ks) {
                short8 bh  = *(const short8*)(BH + (size_t)gcol * K + ks * 32 + lk);
                short8 blv = *(const short8*)(BL + (size_t)gcol * K + ks * 32 + lk);
                acc[f] = __builtin_amdgcn_mfma_f32_16x16x32_bf16(ahv[ks], bh,      acc[f], 0, 0, 0);
                acc[f] = __builtin_amdgcn_mfma_f32_16x16x32_bf16(alv[ks], bh,      acc[f], 0, 0, 0);
                acc[f] = __builtin_amdgcn_mfma_f32_16x16x32_bf16(ahv[ks], blv,     acc[f], 0, 0, 0);
            }
        }
    }
    int rbase = row0 + (lane >> 4) * 4;
    #pragma unroll
    for (int f = 0; f < NFRAG; ++f) {
        float cs = 0.f, css = 0.f;
        if (active) {
            int gcol = gy * NC + f * 16 + lrow;
            float bv = bias[gcol];
            #pragma unroll
            for (int r = 0; r < 4; ++r) {
                float v = acc[f][r] + bv;
                Cf[(size_t)(rbase + r) * NN + gcol] = v;
                cs += v;
                css += v * v;
            }
            cs += __shfl_xor(cs, 16);  css += __shfl_xor(css, 16);
            cs += __shfl_xor(cs, 32);  css += __shfl_xor(css, 32);
        }
        if (lane < 16) {
            red[w][0][f * 16 + lrow] = cs;
            red[w][1][f * 16 + lrow] = css;
        }
    }
    __syncthreads();
    int tid = threadIdx.x;
    for (int c = tid; c < NC; c += 256) {
        float v = red[0][0][c] + red[1][0][c] + red[2][0][c] + red[3][0][c];
        Ps[((size_t)gy * NBLK + blockIdx.x) * NC + c] = v;
    }
    for (int c = tid; c < NC; c += 256) {
        float v = red[0][1][c] + red[1][1][c] + red[2][1][c] + red[3][1][c];
        Pss[((size_t)gy * NBLK + blockIdx.x) * NC + c] = v;
    }
}

// ==== GEMM2: f32 A front-loaded, fused BN+ReLU+split in-register ====
template<int K, int NN, int NC>
__global__ __launch_bounds__(256) void gemm_bn(const float* __restrict__ A,
                                               const unsigned short* __restrict__ BH,
                                               const unsigned short* __restrict__ BL,
                                               const float* __restrict__ bias,
                                               const float* __restrict__ bn_a,
                                               const float* __restrict__ bn_b,
                                               float* __restrict__ Cf,
                                               float* __restrict__ Ps,
                                               float* __restrict__ Pss) {
    constexpr int NFRAG = NC / 16;
    constexpr int KS = K / 32;
    __shared__ float red[4][2][NC];
    int w = threadIdx.x >> 6, lane = threadIdx.x & 63;
    int row0 = (blockIdx.x * 4 + w) * 16;
    int gy = blockIdx.y;
    bool active = row0 < N_NODES;
    int lrow = lane & 15;
    int lk   = (lane >> 4) * 8;
    f32x4 acc[NFRAG];
    #pragma unroll
    for (int f = 0; f < NFRAG; ++f) acc[f] = (f32x4){0.f, 0.f, 0.f, 0.f};
    if (active) {
        const float* Ap = A + (size_t)(row0 + lrow) * K + lk;
        // front-load ALL A data (2*KS independent 16B loads in flight)
        float4 a0[KS], a1[KS];
        #pragma unroll
        for (int ks = 0; ks < KS; ++ks) {
            a0[ks] = *(const float4*)(Ap + ks * 32);
            a1[ks] = *(const float4*)(Ap + ks * 32 + 4);
        }
        // BN + ReLU + split into bf16 hi/lo fragments
        short8 ahv[KS], alv[KS];
        #pragma unroll
        for (int ks = 0; ks < KS; ++ks) {
            int k0 = ks * 32 + lk;
            float4 ba0 = *(const float4*)(bn_a + k0);
            float4 ba1 = *(const float4*)(bn_a + k0 + 4);
            float4 bb0 = *(const float4*)(bn_b + k0);
            float4 bb1 = *(const float4*)(bn_b + k0 + 4);
            float av[8] = {a0[ks].x, a0[ks].y, a0[ks].z, a0[ks].w,
                           a1[ks].x, a1[ks].y, a1[ks].z, a1[ks].w};
            float aa[8] = {ba0.x, ba0.y, ba0.z, ba0.w, ba1.x, ba1.y, ba1.z, ba1.w};
            float ab[8] = {bb0.x, bb0.y, bb0.z, bb0.w, bb1.x, bb1.y, bb1.z, bb1.w};
            #pragma unroll
            for (int j = 0; j < 8; ++j) {
                float v = fmaxf(fmaf(aa[j], av[j], ab[j]), 0.f);
                unsigned short hi = f32_to_bf16(v);
                ahv[ks][j] = (short)hi;
                alv[ks][j] = (short)f32_to_bf16(v - bf16_to_f32(hi));
            }
        }
        #pragma unroll
        for (int f = 0; f < NFRAG; ++f) {
            int gcol = gy * NC + f * 16 + lrow;
            #pragma unroll
            for (int ks = 0; ks < KS; ++ks) {
                short8 bh  = *(const short8*)(BH + (size_t)gcol * K + ks * 32 + lk);
                short8 blv = *(const short8*)(BL + (size_t)gcol * K + ks * 32 + lk);
                acc[f] = __builtin_amdgcn_mfma_f32_16x16x32_bf16(ahv[ks], bh,  acc[f], 0, 0, 0);
                acc[f] = __builtin_amdgcn_mfma_f32_16x16x32_bf16(alv[ks], bh,  acc[f], 0, 0, 0);
                acc[f] = __builtin_amdgcn_mfma_f32_16x16x32_bf16(ahv[ks], blv, acc[f], 0, 0, 0);
            }
        }
    }
    int rbase = row0 + (lane >> 4) * 4;
    #pragma unroll
    for (int f = 0; f < NFRAG; ++f) {
        float cs = 0.f, css = 0.f;
        if (active) {
            int gcol = gy * NC + f * 16 + lrow;
            float bv = bias[gcol];
            #pragma unroll
            for (int r = 0; r < 4; ++r) {
                float v = acc[f][r] + bv;
                Cf[(size_t)(rbase + r) * NN + gcol] = v;
                cs += v;
                css += v * v;
            }
            cs += __shfl_xor(cs, 16);  css += __shfl_xor(css, 16);
            cs += __shfl_xor(cs, 32);  css += __shfl_xor(css, 32);
        }
        if (lane < 16) {
            red[w][0][f * 16 + lrow] = cs;
            red[w][1][f * 16 + lrow] = css;
        }
    }
    __syncthreads();
    int tid = threadIdx.x;
    for (int c = tid; c < NC; c += 256) {
        float v = red[0][0][c] + red[1][0][c] + red[2][0][c] + red[3][0][c];
        Ps[((size_t)gy * NBLK + blockIdx.x) * NC + c] = v;
    }
    for (int c = tid; c < NC; c += 256) {
        float v = red[0][1][c] + red[1][1][c] + red[2][1][c] + red[3][1][c];
        Pss[((size_t)gy * NBLK + blockIdx.x) * NC + c] = v;
    }
}

// ---- reduce partials + BN coefficients; one wave per column ----
__global__ void reduce_bn(const float* __restrict__ Ps, const float* __restrict__ Pss,
                          const float* __restrict__ g, const float* __restrict__ bvec,
                          float* __restrict__ a, float* __restrict__ bias,
                          int NC, int C) {
    int w = threadIdx.x >> 6, lane = threadIdx.x & 63;
    int col = blockIdx.x * 4 + w;
    if (col >= C) return;
    int gy = col / NC, lc = col - gy * NC;
    const float* ps  = Ps  + ((size_t)gy * NBLK) * NC + lc;
    const float* pss = Pss + ((size_t)gy * NBLK) * NC + lc;
    float s = 0.f, ss = 0.f;
    for (int b = lane; b < NBLK; b += 64) {
        s  += ps[(size_t)b * NC];
        ss += pss[(size_t)b * NC];
    }
    #pragma unroll
    for (int d = 1; d < 64; d <<= 1) {
        s += __shfl_xor(s, d);
        ss += __shfl_xor(ss, d);
    }
    if (lane == 0) {
        float mu  = s * (1.0f / N_NODES);
        float var = ss * (1.0f / N_NODES) - mu * mu;
        float inv = rsqrtf(var + BN_EPS);
        float av = g[col] * inv;
        a[col] = av;
        bias[col] = bvec[col] - mu * av;
    }
}

// ---- o = a*z + bias (+relu), f32; optional bf16 mirror ----
__global__ void bn_apply(const float* __restrict__ z, const float* __restrict__ a,
                         const float* __restrict__ bias, float* __restrict__ o,
                         unsigned short* __restrict__ hbout,
                         int total, int nmask, int relu) {
    int i = blockIdx.x * 256 + threadIdx.x;
    int base = i * 4;
    if (base >= total) return;
    int col = base & nmask;
    float4 v = *(const float4*)(z + base);
    float4 r;
    r.x = a[col + 0] * v.x + bias[col + 0];
    r.y = a[col + 1] * v.y + bias[col + 1];
    r.z = a[col + 2] * v.z + bias[col + 2];
    r.w = a[col + 3] * v.w + bias[col + 3];
    if (relu) {
        r.x = fmaxf(r.x, 0.f); r.y = fmaxf(r.y, 0.f);
        r.z = fmaxf(r.z, 0.f); r.w = fmaxf(r.w, 0.f);
    }
    *(float4*)(o + base) = r;
    if (hbout) {
        ushort4 u;
        u.x = f32_to_bf16(r.x); u.y = f32_to_bf16(r.y);
        u.z = f32_to_bf16(r.z); u.w = f32_to_bf16(r.w);
        *(ushort4*)(hbout + base) = u;
    }
}

extern "C" void kernel_launch(void* const* d_in, const int* in_sizes, int n_in,
                              void* d_out, int out_size, void* d_ws, size_t ws_size,
                              hipStream_t stream) {
    const float* x      = (const float*)d_in[0];
    const int*   ei     = (const int*)d_in[1];
    const float* ea     = (const float*)d_in[2];
    const float* atom_W = (const float*)d_in[3];
    const float* atom_b = (const float*)d_in[4];
    const float* bond_W = (const float*)d_in[5];
    const float* bond_b = (const float*)d_in[6];
    const float* W1     = (const float*)d_in[7];
    const float* b1     = (const float*)d_in[8];
    const float* bn1_g  = (const float*)d_in[9];
    const float* bn1_b  = (const float*)d_in[10];
    const float* W2     = (const float*)d_in[11];
    const float* b2     = (const float*)d_in[12];
    const float* eps    = (const float*)d_in[13];
    const float* bn_g   = (const float*)d_in[14];
    const float* bn_b   = (const float*)d_in[15];
    float* out = (float*)d_out;

    uint8_t* ws = (uint8_t*)d_ws;
    float* h            = (float*)(ws + 0);                    // 25,600,000
    unsigned short* hb  = (unsigned short*)(ws + 25600000);    // 12,800,000
    unsigned short* zh  = (unsigned short*)(ws + 38400000);    // 12,800,000
    unsigned short* zl  = (unsigned short*)(ws + 51200000);    // 12,800,000
    float* z2           = (float*)(ws + 38400000);             // overlaps zh+zl (disjoint lifetime)
    float* y1           = (float*)(ws + 64000000);             // 51,200,000
    unsigned short* eas = (unsigned short*)(ws + 115200000);   // 17,920,000
    unsigned short* W1H = (unsigned short*)(ws + 133120000);   // 327,680 each
    unsigned short* W1L = (unsigned short*)(ws + 133447680);
    unsigned short* W2H = (unsigned short*)(ws + 133775360);
    unsigned short* W2L = (unsigned short*)(ws + 134103040);
    float* coef  = (float*)(ws + 134430720);                   // 4,096
    int* off     = (int*)(ws + 134434816);                     // 200,064
    int* esrc    = (int*)(ws + 134634880);                     // 2,560,000
    float* Ps1   = (float*)(ws + 137194880);                   // 800,768 (2*782*128*4)
    float* Pss1  = (float*)(ws + 137995648);                   // 800,768
    float* Ps2   = (float*)(ws + 138796416);                   // 400,384 (2*782*64*4)
    float* Pss2  = (float*)(ws + 139196800);                   // 400,384
    // setup-only buffers overlapping y1 (dead until first gemm1):
    int* cursor  = (int*)(ws + 64000000);
    int* eidx    = (int*)(ws + 64200064);
    int* deg     = (int*)(ws + 66760064);
    float* a1  = coef;       float* bb1 = a1 + 256;
    float* a2  = bb1 + 256;  float* bb2 = a2 + 128;

    wtrans<<<640, 256, 0, stream>>>(W1, W1H, W1L, 128, 256, LAYERS * 128 * 256);
    wtrans<<<640, 256, 0, stream>>>(W2, W2H, W2L, 256, 128, LAYERS * 256 * 128);

    atom_enc<<<1563, 256, 0, stream>>>(x, atom_W, atom_b, h, hb);

    hipMemsetAsync(deg, 0, 200000, stream);
    count_deg<<<2500, 256, 0, stream>>>(ei, deg);
    scan_off<<<1, 1024, 0, stream>>>(deg, off, cursor);
    fill_csr<<<2500, 256, 0, stream>>>(ei, cursor, esrc, eidx);
    ea_sort<<<2500, 256, 0, stream>>>(eidx, ea, eas);

    for (int l = 0; l < LAYERS; ++l) {
        agg_csr<<<12500, 256, 0, stream>>>(
            off, esrc, (const uint32_t*)eas, bond_W + l * 13 * DIM, bond_b + l * DIM,
            h, (const uint32_t*)hb, eps, l, zh, zl);

        gemm1_split<128, 256, 128><<<dim3(NBLK, 2), 256, 0, stream>>>(
            zh, zl, W1H + l * 256 * 128, W1L + l * 256 * 128, b1 + l * 256,
            y1, Ps1, Pss1);

        reduce_bn<<<64, 256, 0, stream>>>(Ps1, Pss1, bn1_g + l * 256, bn1_b + l * 256,
                                          a1, bb1, 128, 256);

        gemm_bn<256, 128, 64><<<dim3(NBLK, 2), 256, 0, stream>>>(
            y1, W2H + l * 128 * 256, W2L + l * 128 * 256, b2 + l * 128,
            a1, bb1, z2, Ps2, Pss2);

        reduce_bn<<<32, 256, 0, stream>>>(Ps2, Pss2, bn_g + l * 128, bn_b + l * 128,
                                          a2, bb2, 64, 128);

        int last = (l == LAYERS - 1);
        bn_apply<<<6250, 256, 0, stream>>>(
            z2, a2, bb2, last ? out : h, last ? (unsigned short*)nullptr : hb,
            N_NODES * DIM, 127, last ? 0 : 1);
    }
    (void)in_sizes; (void)n_in; (void)out_size; (void)ws_size;
}

// Round 15
// 1437.121 us; speedup vs baseline: 3.3621x; 1.0576x over previous
//
#include <hip/hip_runtime.h>
#include <stdint.h>

#define N_NODES 50000
#define N_EDGES 640000
#define DIM 128
#define IN_DIM 64
#define LAYERS 5
#define BN_EPS 1e-5f
#define NBLK 782   // 782*4 waves*16 rows >= 50000

typedef __attribute__((ext_vector_type(8))) short short8;
typedef __attribute__((ext_vector_type(4))) float f32x4;

__device__ __forceinline__ unsigned short f32_to_bf16(float f) {
    uint32_t u = __float_as_uint(f);
    u += 0x7fffu + ((u >> 16) & 1u);
    return (unsigned short)(u >> 16);
}
__device__ __forceinline__ float bf16_to_f32(unsigned short h) {
    return __uint_as_float(((uint32_t)h) << 16);
}

// ---- weights: W[L][K][NN] -> WT_hi/WT_lo[L][NN][K] (split bf16) ----
__global__ void wtrans(const float* __restrict__ W, unsigned short* __restrict__ WH,
                       unsigned short* __restrict__ WL, int K, int NN, int total) {
    int idx = blockIdx.x * 256 + threadIdx.x;
    if (idx >= total) return;
    int per = K * NN;
    int l = idx / per;
    int r = idx - l * per;
    int k = r / NN;
    int n = r - k * NN;
    float v = W[idx];
    unsigned short hi = f32_to_bf16(v);
    unsigned short lo = f32_to_bf16(v - bf16_to_f32(hi));
    WH[l * per + n * K + k] = hi;
    WL[l * per + n * K + k] = lo;
}

// ---- atom encoder via MFMA: h = x @ atom_W + atom_b (split-bf16 A in-register) ----
__global__ __launch_bounds__(256) void atom_mfma(const float* __restrict__ x,
                                                 const unsigned short* __restrict__ BH,
                                                 const unsigned short* __restrict__ BL,
                                                 const float* __restrict__ bias,
                                                 float* __restrict__ h,
                                                 unsigned short* __restrict__ hb) {
    constexpr int K = IN_DIM;       // 64
    constexpr int NN = DIM;         // 128
    constexpr int NFRAG = NN / 16;  // 8
    constexpr int KS = K / 32;      // 2
    int w = threadIdx.x >> 6, lane = threadIdx.x & 63;
    int row0 = (blockIdx.x * 4 + w) * 16;
    if (row0 >= N_NODES) return;    // no barriers below — safe
    int lrow = lane & 15;
    int lk   = (lane >> 4) * 8;
    const float* Ap = x + (size_t)(row0 + lrow) * K + lk;
    float4 a0[KS], a1[KS];
    #pragma unroll
    for (int ks = 0; ks < KS; ++ks) {
        a0[ks] = *(const float4*)(Ap + ks * 32);
        a1[ks] = *(const float4*)(Ap + ks * 32 + 4);
    }
    short8 ahv[KS], alv[KS];
    #pragma unroll
    for (int ks = 0; ks < KS; ++ks) {
        float av[8] = {a0[ks].x, a0[ks].y, a0[ks].z, a0[ks].w,
                       a1[ks].x, a1[ks].y, a1[ks].z, a1[ks].w};
        #pragma unroll
        for (int j = 0; j < 8; ++j) {
            unsigned short hi = f32_to_bf16(av[j]);
            ahv[ks][j] = (short)hi;
            alv[ks][j] = (short)f32_to_bf16(av[j] - bf16_to_f32(hi));
        }
    }
    f32x4 acc[NFRAG];
    #pragma unroll
    for (int f = 0; f < NFRAG; ++f) acc[f] = (f32x4){0.f, 0.f, 0.f, 0.f};
    #pragma unroll
    for (int f = 0; f < NFRAG; ++f) {
        int gcol = f * 16 + lrow;
        #pragma unroll
        for (int ks = 0; ks < KS; ++ks) {
            short8 bh  = *(const short8*)(BH + (size_t)gcol * K + ks * 32 + lk);
            short8 blv = *(const short8*)(BL + (size_t)gcol * K + ks * 32 + lk);
            acc[f] = __builtin_amdgcn_mfma_f32_16x16x32_bf16(ahv[ks], bh,  acc[f], 0, 0, 0);
            acc[f] = __builtin_amdgcn_mfma_f32_16x16x32_bf16(alv[ks], bh,  acc[f], 0, 0, 0);
            acc[f] = __builtin_amdgcn_mfma_f32_16x16x32_bf16(ahv[ks], blv, acc[f], 0, 0, 0);
        }
    }
    int rbase = row0 + (lane >> 4) * 4;
    #pragma unroll
    for (int f = 0; f < NFRAG; ++f) {
        int gcol = f * 16 + lrow;
        float bv = bias[gcol];
        #pragma unroll
        for (int r = 0; r < 4; ++r) {
            float v = acc[f][r] + bv;
            size_t idx = (size_t)(rbase + r) * NN + gcol;
            h[idx] = v;
            hb[idx] = f32_to_bf16(v);
        }
    }
}

// ==== CSR build ====
__global__ void count_deg(const int* __restrict__ ei, int* __restrict__ deg) {
    int e = blockIdx.x * 256 + threadIdx.x;
    if (e < N_EDGES) atomicAdd(&deg[ei[N_EDGES + e]], 1);
}

__global__ __launch_bounds__(1024) void scan_off(const int* __restrict__ deg,
                                                 int* __restrict__ off,
                                                 int* __restrict__ cursor) {
    __shared__ int wsum[16];
    __shared__ int carry_s;
    int tid = threadIdx.x, w = tid >> 6, lane = tid & 63;
    if (tid == 0) carry_s = 0;
    __syncthreads();
    for (int base = 0; base < N_NODES; base += 1024) {
        int i = base + tid;
        int v = (i < N_NODES) ? deg[i] : 0;
        int x = v;
        #pragma unroll
        for (int d = 1; d < 64; d <<= 1) {
            int t = __shfl_up(x, d);
            if (lane >= d) x += t;
        }
        if (lane == 63) wsum[w] = x;
        __syncthreads();
        if (w == 0) {
            int s_ = (lane < 16) ? wsum[lane] : 0;
            #pragma unroll
            for (int d = 1; d < 16; d <<= 1) {
                int t = __shfl_up(s_, d);
                if (lane >= d) s_ += t;
            }
            if (lane < 16) wsum[lane] = s_;
        }
        __syncthreads();
        int wbase = (w == 0) ? 0 : wsum[w - 1];
        int excl = carry_s + wbase + x - v;
        if (i < N_NODES) { off[i] = excl; cursor[i] = excl; }
        int chunk_total = wsum[15];
        __syncthreads();
        if (tid == 0) carry_s += chunk_total;
        __syncthreads();
    }
    if (threadIdx.x == 0) off[N_NODES] = carry_s;
}

__global__ void fill_csr(const int* __restrict__ ei, int* __restrict__ cursor,
                         int* __restrict__ esrc, int* __restrict__ eidx) {
    int e = blockIdx.x * 256 + threadIdx.x;
    if (e >= N_EDGES) return;
    int dst = ei[N_EDGES + e];
    int pos = atomicAdd(&cursor[dst], 1);
    esrc[pos] = ei[e];
    eidx[pos] = e;
}

// ---- CSR-ordered bf16 edge features: eas[s][14] (13 + pad), 28B rows ----
__global__ void ea_sort(const int* __restrict__ eidx, const float* __restrict__ ea,
                        unsigned short* __restrict__ eas) {
    int s = blockIdx.x * 256 + threadIdx.x;
    if (s >= N_EDGES) return;
    int e = eidx[s];
    const float* p = ea + (size_t)e * 13;
    unsigned short* q = eas + (size_t)s * 14;
    #pragma unroll
    for (int k = 0; k < 13; ++k) q[k] = f32_to_bf16(p[k]);
    q[13] = 0;
}

// ==== fused per-node aggregation; sequential bf16 ea, bf16 h gather, depth-2 dbuf ====
__global__ __launch_bounds__(256) void agg_csr(const int* __restrict__ off,
                                               const int* __restrict__ esrc,
                                               const uint32_t* __restrict__ eas32,
                                               const float* __restrict__ bW,
                                               const float* __restrict__ bb,
                                               const float* __restrict__ h,
                                               const uint32_t* __restrict__ hb32,
                                               const float* __restrict__ eps,
                                               int l,
                                               unsigned short* __restrict__ zh,
                                               unsigned short* __restrict__ zl) {
    __shared__ float Wl[13 * DIM];
    __shared__ float bl[DIM];
    for (int i = threadIdx.x; i < 13 * DIM; i += 256) Wl[i] = bW[i];
    if (threadIdx.x < DIM) bl[threadIdx.x] = bb[threadIdx.x];
    __syncthreads();
    int w = threadIdx.x >> 6, lane = threadIdx.x & 63;
    int n = blockIdx.x * 4 + w;
    int c0 = lane * 2;
    float w0[13], w1[13];
    #pragma unroll
    for (int k = 0; k < 13; ++k) { w0[k] = Wl[k * DIM + c0]; w1[k] = Wl[k * DIM + c0 + 1]; }
    float b0 = bl[c0], b1v = bl[c0 + 1];
    int e0 = __builtin_amdgcn_readfirstlane(off[n]);
    int e1 = __builtin_amdgcn_readfirstlane(off[n + 1]);
    int deg = e1 - e0;
    int t = e0 + lane;
    int my_src = (t < e1) ? esrc[t] : 0;
    int cnt = deg < 64 ? deg : 64;
    float ax = 0.f, ay = 0.f;

    uint32_t eA[7], eB[7];
    uint32_t hA = 0, hB = 0;

    auto LOAD = [&](int i, uint32_t* eD, uint32_t& hD) {
        int s_ = __builtin_amdgcn_readlane(my_src, i);
        const uint32_t* p = eas32 + (size_t)(e0 + i) * 7;   // uniform -> s_load
        #pragma unroll
        for (int k = 0; k < 7; ++k) eD[k] = p[k];
        hD = hb32[s_ * (DIM / 2) + lane];
    };
    auto COMPUTE = [&](const uint32_t* eD, uint32_t hD) {
        float f[13];
        #pragma unroll
        for (int k = 0; k < 6; ++k) {
            f[2 * k]     = __uint_as_float(eD[k] << 16);
            f[2 * k + 1] = __uint_as_float(eD[k] & 0xffff0000u);
        }
        f[12] = __uint_as_float(eD[6] << 16);
        float ex = b0, ey = b1v;
        #pragma unroll
        for (int k = 0; k < 13; ++k) {
            ex = fmaf(f[k], w0[k], ex);
            ey = fmaf(f[k], w1[k], ey);
        }
        float hx = __uint_as_float(hD << 16);
        float hy = __uint_as_float(hD & 0xffff0000u);
        ax += fmaxf(hx + ex, 0.f);
        ay += fmaxf(hy + ey, 0.f);
    };

    if (cnt > 0) LOAD(0, eA, hA);
    for (int i = 0; i < cnt; i += 2) {
        if (i + 1 < cnt) LOAD(i + 1, eB, hB);
        COMPUTE(eA, hA);
        if (i + 2 < cnt) LOAD(i + 2, eA, hA);
        if (i + 1 < cnt) COMPUTE(eB, hB);
    }
    // cold tail for deg > 64
    for (int s2 = e0 + 64; s2 < e1; ++s2) {
        int src = __builtin_amdgcn_readfirstlane(esrc[s2]);
        uint32_t eT[7];
        const uint32_t* p = eas32 + (size_t)s2 * 7;
        #pragma unroll
        for (int k = 0; k < 7; ++k) eT[k] = p[k];
        COMPUTE(eT, hb32[src * (DIM / 2) + lane]);
    }

    float sc = 1.0f + eps[l];
    float2 hn = *(const float2*)(h + (size_t)n * DIM + c0);
    float zx = fmaf(sc, hn.x, ax);
    float zy = fmaf(sc, hn.y, ay);
    unsigned short hx = f32_to_bf16(zx), hy = f32_to_bf16(zy);
    ushort2 hiv, lov;
    hiv.x = hx; hiv.y = hy;
    lov.x = f32_to_bf16(zx - bf16_to_f32(hx));
    lov.y = f32_to_bf16(zy - bf16_to_f32(hy));
    *(ushort2*)(zh + (size_t)n * DIM + c0) = hiv;
    *(ushort2*)(zl + (size_t)n * DIM + c0) = lov;
}

// ==== GEMM1: split-pair A front-loaded into registers, then MFMA ====
template<int K, int NN, int NC>
__global__ __launch_bounds__(256) void gemm1_split(const unsigned short* __restrict__ AH,
                                                   const unsigned short* __restrict__ AL,
                                                   const unsigned short* __restrict__ BH,
                                                   const unsigned short* __restrict__ BL,
                                                   const float* __restrict__ bias,
                                                   float* __restrict__ Cf,
                                                   float* __restrict__ Ps,
                                                   float* __restrict__ Pss) {
    constexpr int NFRAG = NC / 16;
    constexpr int KS = K / 32;
    __shared__ float red[4][2][NC];
    int w = threadIdx.x >> 6, lane = threadIdx.x & 63;
    int row0 = (blockIdx.x * 4 + w) * 16;
    int gy = blockIdx.y;
    bool active = row0 < N_NODES;
    int lrow = lane & 15;
    int lk   = (lane >> 4) * 8;
    f32x4 acc[NFRAG];
    #pragma unroll
    for (int f = 0; f < NFRAG; ++f) acc[f] = (f32x4){0.f, 0.f, 0.f, 0.f};
    if (active) {
        int abase = (row0 + lrow) * K + lk;
        short8 ahv[KS], alv[KS];
        #pragma unroll
        for (int ks = 0; ks < KS; ++ks) {
            ahv[ks] = *(const short8*)(AH + abase + ks * 32);
            alv[ks] = *(const short8*)(AL + abase + ks * 32);
        }
        #pragma unroll
        for (int f = 0; f < NFRAG; ++f) {
            int gcol = gy * NC + f * 16 + lrow;
            #pragma unroll
            for (int ks = 0; ks < KS; ++ks) {
                short8 bh  = *(const short8*)(BH + (size_t)gcol * K + ks * 32 + lk);
                short8 blv = *(const short8*)(BL + (size_t)gcol * K + ks * 32 + lk);
                acc[f] = __builtin_amdgcn_mfma_f32_16x16x32_bf16(ahv[ks], bh,  acc[f], 0, 0, 0);
                acc[f] = __builtin_amdgcn_mfma_f32_16x16x32_bf16(alv[ks], bh,  acc[f], 0, 0, 0);
                acc[f] = __builtin_amdgcn_mfma_f32_16x16x32_bf16(ahv[ks], blv, acc[f], 0, 0, 0);
            }
        }
    }
    int rbase = row0 + (lane >> 4) * 4;
    #pragma unroll
    for (int f = 0; f < NFRAG; ++f) {
        float cs = 0.f, css = 0.f;
        if (active) {
            int gcol = gy * NC + f * 16 + lrow;
            float bv = bias[gcol];
            #pragma unroll
            for (int r = 0; r < 4; ++r) {
                float v = acc[f][r] + bv;
                Cf[(size_t)(rbase + r) * NN + gcol] = v;
                cs += v;
                css += v * v;
            }
            cs += __shfl_xor(cs, 16);  css += __shfl_xor(css, 16);
            cs += __shfl_xor(cs, 32);  css += __shfl_xor(css, 32);
        }
        if (lane < 16) {
            red[w][0][f * 16 + lrow] = cs;
            red[w][1][f * 16 + lrow] = css;
        }
    }
    __syncthreads();
    int tid = threadIdx.x;
    for (int c = tid; c < NC; c += 256) {
        float v = red[0][0][c] + red[1][0][c] + red[2][0][c] + red[3][0][c];
        Ps[((size_t)gy * NBLK + blockIdx.x) * NC + c] = v;
    }
    for (int c = tid; c < NC; c += 256) {
        float v = red[0][1][c] + red[1][1][c] + red[2][1][c] + red[3][1][c];
        Pss[((size_t)gy * NBLK + blockIdx.x) * NC + c] = v;
    }
}

// ==== GEMM2: f32 A front-loaded, fused BN+ReLU+split in-register ====
template<int K, int NN, int NC>
__global__ __launch_bounds__(256) void gemm_bn(const float* __restrict__ A,
                                               const unsigned short* __restrict__ BH,
                                               const unsigned short* __restrict__ BL,
                                               const float* __restrict__ bias,
                                               const float* __restrict__ bn_a,
                                               const float* __restrict__ bn_b,
                                               float* __restrict__ Cf,
                                               float* __restrict__ Ps,
                                               float* __restrict__ Pss) {
    constexpr int NFRAG = NC / 16;
    constexpr int KS = K / 32;
    __shared__ float red[4][2][NC];
    int w = threadIdx.x >> 6, lane = threadIdx.x & 63;
    int row0 = (blockIdx.x * 4 + w) * 16;
    int gy = blockIdx.y;
    bool active = row0 < N_NODES;
    int lrow = lane & 15;
    int lk   = (lane >> 4) * 8;
    f32x4 acc[NFRAG];
    #pragma unroll
    for (int f = 0; f < NFRAG; ++f) acc[f] = (f32x4){0.f, 0.f, 0.f, 0.f};
    if (active) {
        const float* Ap = A + (size_t)(row0 + lrow) * K + lk;
        float4 a0[KS], a1[KS];
        #pragma unroll
        for (int ks = 0; ks < KS; ++ks) {
            a0[ks] = *(const float4*)(Ap + ks * 32);
            a1[ks] = *(const float4*)(Ap + ks * 32 + 4);
        }
        short8 ahv[KS], alv[KS];
        #pragma unroll
        for (int ks = 0; ks < KS; ++ks) {
            int k0 = ks * 32 + lk;
            float4 ba0 = *(const float4*)(bn_a + k0);
            float4 ba1 = *(const float4*)(bn_a + k0 + 4);
            float4 bb0 = *(const float4*)(bn_b + k0);
            float4 bb1 = *(const float4*)(bn_b + k0 + 4);
            float av[8] = {a0[ks].x, a0[ks].y, a0[ks].z, a0[ks].w,
                           a1[ks].x, a1[ks].y, a1[ks].z, a1[ks].w};
            float aa[8] = {ba0.x, ba0.y, ba0.z, ba0.w, ba1.x, ba1.y, ba1.z, ba1.w};
            float ab[8] = {bb0.x, bb0.y, bb0.z, bb0.w, bb1.x, bb1.y, bb1.z, bb1.w};
            #pragma unroll
            for (int j = 0; j < 8; ++j) {
                float v = fmaxf(fmaf(aa[j], av[j], ab[j]), 0.f);
                unsigned short hi = f32_to_bf16(v);
                ahv[ks][j] = (short)hi;
                alv[ks][j] = (short)f32_to_bf16(v - bf16_to_f32(hi));
            }
        }
        #pragma unroll
        for (int f = 0; f < NFRAG; ++f) {
            int gcol = gy * NC + f * 16 + lrow;
            #pragma unroll
            for (int ks = 0; ks < KS; ++ks) {
                short8 bh  = *(const short8*)(BH + (size_t)gcol * K + ks * 32 + lk);
                short8 blv = *(const short8*)(BL + (size_t)gcol * K + ks * 32 + lk);
                acc[f] = __builtin_amdgcn_mfma_f32_16x16x32_bf16(ahv[ks], bh,  acc[f], 0, 0, 0);
                acc[f] = __builtin_amdgcn_mfma_f32_16x16x32_bf16(alv[ks], bh,  acc[f], 0, 0, 0);
                acc[f] = __builtin_amdgcn_mfma_f32_16x16x32_bf16(ahv[ks], blv, acc[f], 0, 0, 0);
            }
        }
    }
    int rbase = row0 + (lane >> 4) * 4;
    #pragma unroll
    for (int f = 0; f < NFRAG; ++f) {
        float cs = 0.f, css = 0.f;
        if (active) {
            int gcol = gy * NC + f * 16 + lrow;
            float bv = bias[gcol];
            #pragma unroll
            for (int r = 0; r < 4; ++r) {
                float v = acc[f][r] + bv;
                Cf[(size_t)(rbase + r) * NN + gcol] = v;
                cs += v;
                css += v * v;
            }
            cs += __shfl_xor(cs, 16);  css += __shfl_xor(css, 16);
            cs += __shfl_xor(cs, 32);  css += __shfl_xor(css, 32);
        }
        if (lane < 16) {
            red[w][0][f * 16 + lrow] = cs;
            red[w][1][f * 16 + lrow] = css;
        }
    }
    __syncthreads();
    int tid = threadIdx.x;
    for (int c = tid; c < NC; c += 256) {
        float v = red[0][0][c] + red[1][0][c] + red[2][0][c] + red[3][0][c];
        Ps[((size_t)gy * NBLK + blockIdx.x) * NC + c] = v;
    }
    for (int c = tid; c < NC; c += 256) {
        float v = red[0][1][c] + red[1][1][c] + red[2][1][c] + red[3][1][c];
        Pss[((size_t)gy * NBLK + blockIdx.x) * NC + c] = v;
    }
}

// ---- reduce partials + BN coefficients; one wave per column ----
__global__ void reduce_bn(const float* __restrict__ Ps, const float* __restrict__ Pss,
                          const float* __restrict__ g, const float* __restrict__ bvec,
                          float* __restrict__ a, float* __restrict__ bias,
                          int NC, int C) {
    int w = threadIdx.x >> 6, lane = threadIdx.x & 63;
    int col = blockIdx.x * 4 + w;
    if (col >= C) return;
    int gy = col / NC, lc = col - gy * NC;
    const float* ps  = Ps  + ((size_t)gy * NBLK) * NC + lc;
    const float* pss = Pss + ((size_t)gy * NBLK) * NC + lc;
    float s = 0.f, ss = 0.f;
    for (int b = lane; b < NBLK; b += 64) {
        s  += ps[(size_t)b * NC];
        ss += pss[(size_t)b * NC];
    }
    #pragma unroll
    for (int d = 1; d < 64; d <<= 1) {
        s += __shfl_xor(s, d);
        ss += __shfl_xor(ss, d);
    }
    if (lane == 0) {
        float mu  = s * (1.0f / N_NODES);
        float var = ss * (1.0f / N_NODES) - mu * mu;
        float inv = rsqrtf(var + BN_EPS);
        float av = g[col] * inv;
        a[col] = av;
        bias[col] = bvec[col] - mu * av;
    }
}

// ---- o = a*z + bias (+relu), f32; optional bf16 mirror ----
__global__ void bn_apply(const float* __restrict__ z, const float* __restrict__ a,
                         const float* __restrict__ bias, float* __restrict__ o,
                         unsigned short* __restrict__ hbout,
                         int total, int nmask, int relu) {
    int i = blockIdx.x * 256 + threadIdx.x;
    int base = i * 4;
    if (base >= total) return;
    int col = base & nmask;
    float4 v = *(const float4*)(z + base);
    float4 r;
    r.x = a[col + 0] * v.x + bias[col + 0];
    r.y = a[col + 1] * v.y + bias[col + 1];
    r.z = a[col + 2] * v.z + bias[col + 2];
    r.w = a[col + 3] * v.w + bias[col + 3];
    if (relu) {
        r.x = fmaxf(r.x, 0.f); r.y = fmaxf(r.y, 0.f);
        r.z = fmaxf(r.z, 0.f); r.w = fmaxf(r.w, 0.f);
    }
    *(float4*)(o + base) = r;
    if (hbout) {
        ushort4 u;
        u.x = f32_to_bf16(r.x); u.y = f32_to_bf16(r.y);
        u.z = f32_to_bf16(r.z); u.w = f32_to_bf16(r.w);
        *(ushort4*)(hbout + base) = u;
    }
}

extern "C" void kernel_launch(void* const* d_in, const int* in_sizes, int n_in,
                              void* d_out, int out_size, void* d_ws, size_t ws_size,
                              hipStream_t stream) {
    const float* x      = (const float*)d_in[0];
    const int*   ei     = (const int*)d_in[1];
    const float* ea     = (const float*)d_in[2];
    const float* atom_W = (const float*)d_in[3];
    const float* atom_b = (const float*)d_in[4];
    const float* bond_W = (const float*)d_in[5];
    const float* bond_b = (const float*)d_in[6];
    const float* W1     = (const float*)d_in[7];
    const float* b1     = (const float*)d_in[8];
    const float* bn1_g  = (const float*)d_in[9];
    const float* bn1_b  = (const float*)d_in[10];
    const float* W2     = (const float*)d_in[11];
    const float* b2     = (const float*)d_in[12];
    const float* eps    = (const float*)d_in[13];
    const float* bn_g   = (const float*)d_in[14];
    const float* bn_b   = (const float*)d_in[15];
    float* out = (float*)d_out;

    uint8_t* ws = (uint8_t*)d_ws;
    float* h            = (float*)(ws + 0);                    // 25,600,000
    unsigned short* hb  = (unsigned short*)(ws + 25600000);    // 12,800,000
    unsigned short* zh  = (unsigned short*)(ws + 38400000);    // 12,800,000
    unsigned short* zl  = (unsigned short*)(ws + 51200000);    // 12,800,000
    float* z2           = (float*)(ws + 38400000);             // overlaps zh+zl (disjoint lifetime)
    float* y1           = (float*)(ws + 64000000);             // 51,200,000
    unsigned short* eas = (unsigned short*)(ws + 115200000);   // 17,920,000
    unsigned short* W1H = (unsigned short*)(ws + 133120000);   // 327,680 each
    unsigned short* W1L = (unsigned short*)(ws + 133447680);
    unsigned short* W2H = (unsigned short*)(ws + 133775360);
    unsigned short* W2L = (unsigned short*)(ws + 134103040);
    float* coef  = (float*)(ws + 134430720);                   // 4,096
    int* off     = (int*)(ws + 134434816);                     // 200,064
    int* esrc    = (int*)(ws + 134634880);                     // 2,560,000
    float* Ps1   = (float*)(ws + 137194880);                   // 800,768 (4*782*64*4)
    float* Pss1  = (float*)(ws + 137995648);                   // 800,768
    float* Ps2   = (float*)(ws + 138796416);                   // 400,384 (2*782*64*4)
    float* Pss2  = (float*)(ws + 139196800);                   // 400,384
    unsigned short* AWH = (unsigned short*)(ws + 139597184);   // 16,384 (64*128*2)
    unsigned short* AWL = (unsigned short*)(ws + 139613568);   // 16,384 -> end 139,629,952
    // setup-only buffers overlapping y1 (dead until first gemm1):
    int* cursor  = (int*)(ws + 64000000);
    int* eidx    = (int*)(ws + 64200064);
    int* deg     = (int*)(ws + 66760064);
    float* a1  = coef;       float* bb1 = a1 + 256;
    float* a2  = bb1 + 256;  float* bb2 = a2 + 128;

    wtrans<<<640, 256, 0, stream>>>(W1, W1H, W1L, 128, 256, LAYERS * 128 * 256);
    wtrans<<<640, 256, 0, stream>>>(W2, W2H, W2L, 256, 128, LAYERS * 256 * 128);
    wtrans<<<32, 256, 0, stream>>>(atom_W, AWH, AWL, 64, 128, 64 * 128);

    atom_mfma<<<NBLK, 256, 0, stream>>>(x, AWH, AWL, atom_b, h, hb);

    hipMemsetAsync(deg, 0, 200000, stream);
    count_deg<<<2500, 256, 0, stream>>>(ei, deg);
    scan_off<<<1, 1024, 0, stream>>>(deg, off, cursor);
    fill_csr<<<2500, 256, 0, stream>>>(ei, cursor, esrc, eidx);
    ea_sort<<<2500, 256, 0, stream>>>(eidx, ea, eas);

    for (int l = 0; l < LAYERS; ++l) {
        agg_csr<<<12500, 256, 0, stream>>>(
            off, esrc, (const uint32_t*)eas, bond_W + l * 13 * DIM, bond_b + l * DIM,
            h, (const uint32_t*)hb, eps, l, zh, zl);

        gemm1_split<128, 256, 64><<<dim3(NBLK, 4), 256, 0, stream>>>(
            zh, zl, W1H + l * 256 * 128, W1L + l * 256 * 128, b1 + l * 256,
            y1, Ps1, Pss1);

        reduce_bn<<<64, 256, 0, stream>>>(Ps1, Pss1, bn1_g + l * 256, bn1_b + l * 256,
                                          a1, bb1, 64, 256);

        gemm_bn<256, 128, 64><<<dim3(NBLK, 2), 256, 0, stream>>>(
            y1, W2H + l * 128 * 256, W2L + l * 128 * 256, b2 + l * 128,
            a1, bb1, z2, Ps2, Pss2);

        reduce_bn<<<32, 256, 0, stream>>>(Ps2, Pss2, bn_g + l * 128, bn_b + l * 128,
                                          a2, bb2, 64, 128);

        int last = (l == LAYERS - 1);
        bn_apply<<<6250, 256, 0, stream>>>(
            z2, a2, bb2, last ? out : h, last ? (unsigned short*)nullptr : hb,
            N_NODES * DIM, 127, last ? 0 : 1);
    }
    (void)in_sizes; (void)n_in; (void)out_size; (void)ws_size;
}